// Round 11
// baseline (439.328 us; speedup 1.0000x reference)
//
#include <hip/hip_runtime.h>
#include <cstdint>

#define RELU_COEF 0.05f
#define LEAKY(v) ((v) > 0.f ? (v) : RELU_COEF * (v))

typedef __attribute__((ext_vector_type(8))) short short8;
typedef __attribute__((ext_vector_type(4))) float f32x4;

#define MFMA(acc, a, b) \
    acc = __builtin_amdgcn_mfma_f32_16x16x32_bf16(a, b, acc, 0, 0, 0)

__device__ inline ushort f2bf(float f) {
    union { float f; uint32_t u; } v; v.f = f;
    return (ushort)((v.u + 0x7FFFu + ((v.u >> 16) & 1u)) >> 16);
}
__device__ inline float bf2f(ushort h) {
    union { uint32_t u; float f; } v; v.u = ((uint32_t)h) << 16;
    return v.f;
}
__device__ inline void split8(const float* p, short8& h8, short8& l8) {
    float4 a = *(const float4*)p;
    float4 b = *(const float4*)(p + 4);
    float v[8] = {a.x, a.y, a.z, a.w, b.x, b.y, b.z, b.w};
    short8 hh, ll;
#pragma unroll
    for (int i = 0; i < 8; ++i) {
        ushort hi = f2bf(v[i]);
        hh[i] = (short)hi;
        ll[i] = (short)f2bf(v[i] - bf2f(hi));
    }
    h8 = hh; l8 = ll;
}

// ---------------------------------------------------------------------------
// CSR build
// ---------------------------------------------------------------------------
__global__ __launch_bounds__(256) void hist_kernel(
    const int* __restrict__ ei, int* __restrict__ deg, int E)
{
    int e = blockIdx.x * 256 + threadIdx.x;
    if (e >= E) return;
    atomicAdd(&deg[ei[(size_t)E + e]], 1);
}

__global__ __launch_bounds__(256) void scan1_kernel(
    const int* __restrict__ in, int* __restrict__ out, int* __restrict__ bsum, int N)
{
    __shared__ int ts[256];
    int tid = threadIdx.x;
    int base = blockIdx.x * 1024 + tid * 4;
    int v[4];
    int s = 0;
#pragma unroll
    for (int j = 0; j < 4; ++j) {
        int idx = base + j;
        v[j] = (idx < N) ? in[idx] : 0;
        s += v[j];
    }
    ts[tid] = s;
    __syncthreads();
    for (int off = 1; off < 256; off <<= 1) {
        int t = (tid >= off) ? ts[tid - off] : 0;
        __syncthreads();
        ts[tid] += t;
        __syncthreads();
    }
    int excl = ts[tid] - s;
    if (tid == 255) bsum[blockIdx.x] = ts[255];
    int run = excl;
#pragma unroll
    for (int j = 0; j < 4; ++j) {
        int idx = base + j;
        if (idx < N) out[idx] = run;
        run += v[j];
    }
}

__global__ __launch_bounds__(512) void scan2_kernel(int* bsum, int nb)
{
    __shared__ int ts[512];
    int tid = threadIdx.x;
    int v = (tid < nb) ? bsum[tid] : 0;
    ts[tid] = v;
    __syncthreads();
    for (int off = 1; off < 512; off <<= 1) {
        int t = (tid >= off) ? ts[tid - off] : 0;
        __syncthreads();
        ts[tid] += t;
        __syncthreads();
    }
    if (tid < nb) bsum[tid] = ts[tid] - v;
}

__global__ __launch_bounds__(256) void scan3_kernel(
    int* __restrict__ rowptr, const int* __restrict__ bsum, int N, int E)
{
    int idx = blockIdx.x * 256 + threadIdx.x;
    if (idx < N) rowptr[idx] += bsum[idx >> 10];
    if (idx == 0) rowptr[N] = E;
}

// fill: single 8B packed store per edge (src idx, fp32 weight)
__global__ __launch_bounds__(256) void fill_kernel(
    const int* __restrict__ ei, const float* __restrict__ ea,
    int* __restrict__ cursor, int2* __restrict__ csw, int E)
{
    int e = blockIdx.x * 256 + threadIdx.x;
    if (e >= E) return;
    int t = ei[(size_t)E + e];
    int pos = atomicAdd(&cursor[t], 1);
    csw[pos] = make_int2(ei[e], __float_as_int(ea[e]));
}

// ---------------------------------------------------------------------------
// x -> bf16 copy (gather payload for conv1)
// ---------------------------------------------------------------------------
__global__ __launch_bounds__(256) void xbf_kernel(
    const float* __restrict__ x, ushort* __restrict__ xbf, int total4)
{
    int i = blockIdx.x * 256 + threadIdx.x;
    if (i >= total4) return;
    float4 v = *(const float4*)(x + (size_t)i * 4);
    ushort4 h;
    h.x = f2bf(v.x); h.y = f2bf(v.y); h.z = f2bf(v.z); h.w = f2bf(v.w);
    *(ushort4*)(xbf + (size_t)i * 4) = h;
}

// ---------------------------------------------------------------------------
// Weight prep -> fragment-major split-bf16 layouts (coalesced B loads):
// W1f[kk:4][hl:2][kc:4][n:128][e:8]   (K=128: agg1|x)
// W2f[kk:8][hl:2][kc:4][n:128][e:8]   (K=256: agg2|h1)
// Wgf[kk:6][p:4 (sH,sL,tH,tL)][kc:4][n:128][e:8]  (K=192: h2|x)
// ---------------------------------------------------------------------------
__global__ __launch_bounds__(256) void prep_weights_kernel(
    const float* __restrict__ Wrel1, const float* __restrict__ Wroot1,
    const float* __restrict__ Wrel2, const float* __restrict__ Wroot2,
    const float* __restrict__ Wsig, const float* __restrict__ Wtanh,
    ushort* __restrict__ W1f, ushort* __restrict__ W2f, ushort* __restrict__ Wgf)
{
    int gid = blockIdx.x * 256 + threadIdx.x;
    if (gid < 32768) {
        int e = gid & 7, nn = (gid >> 3) & 127, kc = (gid >> 10) & 3;
        int hl = (gid >> 12) & 1, kk = gid >> 13;
        int k = kk * 32 + kc * 8 + e;
        float v = (k < 64) ? Wrel1[(size_t)k * 128 + nn]
                           : Wroot1[(size_t)(k - 64) * 128 + nn];
        ushort hi = f2bf(v);
        W1f[gid] = hl ? f2bf(v - bf2f(hi)) : hi;
        return;
    }
    int g2 = gid - 32768;
    if (g2 < 65536) {
        int e = g2 & 7, nn = (g2 >> 3) & 127, kc = (g2 >> 10) & 3;
        int hl = (g2 >> 12) & 1, kk = g2 >> 13;
        int k = kk * 32 + kc * 8 + e;
        float v = (k < 128) ? Wrel2[(size_t)k * 128 + nn]
                            : Wroot2[(size_t)(k - 128) * 128 + nn];
        ushort hi = f2bf(v);
        W2f[g2] = hl ? f2bf(v - bf2f(hi)) : hi;
        return;
    }
    int g3 = g2 - 65536;
    if (g3 < 98304) {
        int e = g3 & 7, nn = (g3 >> 3) & 127, kc = (g3 >> 10) & 3;
        int p = (g3 >> 12) & 3, kk = g3 >> 14;
        int k = kk * 32 + kc * 8 + e;
        float v = (p < 2) ? Wsig[(size_t)k * 128 + nn]
                          : Wtanh[(size_t)k * 128 + nn];
        ushort hi = f2bf(v);
        Wgf[g3] = (p & 1) ? f2bf(v - bf2f(hi)) : hi;
    }
}

// ---------------------------------------------------------------------------
// Standalone gather (conv1): agg1bf[node] = bf16( sum w * xbf[src] )
// 16 lanes/node, shfl-broadcast packed (idx,w), 8-deep loads. No LDS.
// ---------------------------------------------------------------------------
__global__ __launch_bounds__(256) void gather64_kernel(
    const ushort* __restrict__ xbf, const int* __restrict__ rowptr,
    const int2* __restrict__ csw, ushort* __restrict__ agg1bf, int N)
{
    int q = threadIdx.x & 15;
    int node = blockIdx.x * 16 + (threadIdx.x >> 4);
    if (node >= N) return;
    float ax = 0.f, ay = 0.f, az = 0.f, aw = 0.f;
    int b = rowptr[node], e = rowptr[node + 1];
    for (int cb = b; cb < e; cb += 16) {
        int cnt = e - cb; if (cnt > 16) cnt = 16;
        int sIdx = 0; float sW = 0.f;
        if (q < cnt) {
            int2 p = csw[cb + q];
            sIdx = p.x; sW = __int_as_float(p.y);
        }
        int j = 0;
        for (; j + 8 <= cnt; j += 8) {
            int si[8]; float wi[8]; ushort4 fv[8];
#pragma unroll
            for (int u = 0; u < 8; ++u) {
                si[u] = __shfl(sIdx, j + u, 16);
                wi[u] = __shfl(sW, j + u, 16);
            }
#pragma unroll
            for (int u = 0; u < 8; ++u)
                fv[u] = *(const ushort4*)(xbf + (size_t)si[u] * 64 + q * 4);
#pragma unroll
            for (int u = 0; u < 8; ++u) {
                ax += wi[u] * bf2f(fv[u].x);
                ay += wi[u] * bf2f(fv[u].y);
                az += wi[u] * bf2f(fv[u].z);
                aw += wi[u] * bf2f(fv[u].w);
            }
        }
        for (; j < cnt; ++j) {
            int s0 = __shfl(sIdx, j, 16); float w0 = __shfl(sW, j, 16);
            ushort4 f0 = *(const ushort4*)(xbf + (size_t)s0 * 64 + q * 4);
            ax += w0 * bf2f(f0.x); ay += w0 * bf2f(f0.y);
            az += w0 * bf2f(f0.z); aw += w0 * bf2f(f0.w);
        }
    }
    ushort4 h;
    h.x = f2bf(ax); h.y = f2bf(ay); h.z = f2bf(az); h.w = f2bf(aw);
    *(ushort4*)(agg1bf + (size_t)node * 64 + q * 4) = h;
}

// ---------------------------------------------------------------------------
// Standalone gather (conv2): agg2bf[node] = bf16( sum w * h1bf[src] )
// 32 lanes/node. No LDS, no barriers -> minimal VGPR, max occupancy.
// ---------------------------------------------------------------------------
__global__ __launch_bounds__(256) void gather128_kernel(
    const ushort* __restrict__ h1bf, const int* __restrict__ rowptr,
    const int2* __restrict__ csw, ushort* __restrict__ agg2bf, int N)
{
    int q = threadIdx.x & 31;
    int node = blockIdx.x * 8 + (threadIdx.x >> 5);
    if (node >= N) return;
    float ax = 0.f, ay = 0.f, az = 0.f, aw = 0.f;
    int b = rowptr[node], e = rowptr[node + 1];
    for (int cb = b; cb < e; cb += 32) {
        int cnt = e - cb; if (cnt > 32) cnt = 32;
        int sIdx = 0; float sW = 0.f;
        if (q < cnt) {
            int2 p = csw[cb + q];
            sIdx = p.x; sW = __int_as_float(p.y);
        }
        int j = 0;
        for (; j + 8 <= cnt; j += 8) {
            int si[8]; float wi[8]; ushort4 fv[8];
#pragma unroll
            for (int u = 0; u < 8; ++u) {
                si[u] = __shfl(sIdx, j + u, 32);
                wi[u] = __shfl(sW, j + u, 32);
            }
#pragma unroll
            for (int u = 0; u < 8; ++u)
                fv[u] = *(const ushort4*)(h1bf + (size_t)si[u] * 128 + q * 4);
#pragma unroll
            for (int u = 0; u < 8; ++u) {
                ax += wi[u] * bf2f(fv[u].x);
                ay += wi[u] * bf2f(fv[u].y);
                az += wi[u] * bf2f(fv[u].z);
                aw += wi[u] * bf2f(fv[u].w);
            }
        }
        for (; j < cnt; ++j) {
            int s0 = __shfl(sIdx, j, 32); float w0 = __shfl(sW, j, 32);
            ushort4 f0 = *(const ushort4*)(h1bf + (size_t)s0 * 128 + q * 4);
            ax += w0 * bf2f(f0.x); ay += w0 * bf2f(f0.y);
            az += w0 * bf2f(f0.z); aw += w0 * bf2f(f0.w);
        }
    }
    ushort4 h;
    h.x = f2bf(ax); h.y = f2bf(ay); h.z = f2bf(az); h.w = f2bf(aw);
    *(ushort4*)(agg2bf + (size_t)node * 128 + q * 4) = h;
}

// ---------------------------------------------------------------------------
// conv1 GEMM (streaming, no LDS/barriers): h1bf = bf16(leaky([agg1|x]@W1+b))
// ---------------------------------------------------------------------------
__global__ __launch_bounds__(256) void conv1_kernel(
    const float* __restrict__ x, const ushort* __restrict__ agg1bf,
    const ushort* __restrict__ W1f, const float* __restrict__ brel,
    ushort* __restrict__ h1bf, int n)
{
    int tid = threadIdx.x;
    int lane = tid & 63;
    int wv = tid >> 6;
    int mr = lane & 15;
    int kc = lane >> 4;
    int i0 = blockIdx.x * 32;
    int t0 = wv * 2;
    const ushort* Wp = W1f + kc * 1024 + t0 * 128 + mr * 8;
    f32x4 acc[2][2] = {};

#pragma unroll
    for (int kk = 0; kk < 2; ++kk) {      // A = agg1bf (K 0..63), bf16 direct
        short8 bH0 = *(const short8*)(Wp + kk * 8192);
        short8 bH1 = *(const short8*)(Wp + kk * 8192 + 128);
        short8 bL0 = *(const short8*)(Wp + kk * 8192 + 4096);
        short8 bL1 = *(const short8*)(Wp + kk * 8192 + 4096 + 128);
#pragma unroll
        for (int sub = 0; sub < 2; ++sub) {
            int row = i0 + sub * 16 + mr; if (row > n - 1) row = n - 1;
            short8 aH = *(const short8*)(agg1bf + (size_t)row * 64 + kk * 32 + kc * 8);
            MFMA(acc[sub][0], aH, bH0); MFMA(acc[sub][0], aH, bL0);
            MFMA(acc[sub][1], aH, bH1); MFMA(acc[sub][1], aH, bL1);
        }
    }
#pragma unroll
    for (int kk = 2; kk < 4; ++kk) {      // A = x (K 64..127), exact split
        short8 bH0 = *(const short8*)(Wp + kk * 8192);
        short8 bH1 = *(const short8*)(Wp + kk * 8192 + 128);
        short8 bL0 = *(const short8*)(Wp + kk * 8192 + 4096);
        short8 bL1 = *(const short8*)(Wp + kk * 8192 + 4096 + 128);
#pragma unroll
        for (int sub = 0; sub < 2; ++sub) {
            int row = i0 + sub * 16 + mr; if (row > n - 1) row = n - 1;
            short8 aH, aL;
            split8(x + (size_t)row * 64 + (kk - 2) * 32 + kc * 8, aH, aL);
            MFMA(acc[sub][0], aH, bH0); MFMA(acc[sub][0], aH, bL0); MFMA(acc[sub][0], aL, bH0);
            MFMA(acc[sub][1], aH, bH1); MFMA(acc[sub][1], aH, bL1); MFMA(acc[sub][1], aL, bH1);
        }
    }

#pragma unroll
    for (int tt = 0; tt < 2; ++tt) {
        int c = (t0 + tt) * 16 + mr;
        float bv = brel[c];
#pragma unroll
        for (int sub = 0; sub < 2; ++sub)
#pragma unroll
            for (int j = 0; j < 4; ++j) {
                int r = i0 + sub * 16 + kc * 4 + j;
                if (r < n)
                    h1bf[(size_t)r * 128 + c] = f2bf(LEAKY(acc[sub][tt][j] + bv));
            }
    }
}

// ---------------------------------------------------------------------------
// conv2 + gate + pool GEMM (streaming): reads agg2bf/h1bf/x, h2 in LDS,
// gate epilogue, run-compressed pooling.
// ---------------------------------------------------------------------------
__global__ __launch_bounds__(256) void conv2_gate_kernel(
    const ushort* __restrict__ agg2bf, const ushort* __restrict__ h1bf,
    const float* __restrict__ x,
    const ushort* __restrict__ W2f, const float* __restrict__ brel,
    const ushort* __restrict__ Wgf, const float* __restrict__ bsig,
    const float* __restrict__ btanh, const int* __restrict__ batch,
    float* __restrict__ pooled, int n)
{
    __shared__ __align__(16) float h2s[32 * 132];   // 16896 B: h2 -> gs
    __shared__ int bS[32];
    float* gs = h2s;                                 // alias (stride 128)

    int tid = threadIdx.x;
    int lane = tid & 63;
    int wv = tid >> 6;
    int mr = lane & 15;
    int kc = lane >> 4;
    int i0 = blockIdx.x * 32;
    int t0 = wv * 2;

    if (tid < 32) {
        int r = i0 + tid;
        bS[tid] = (r < n) ? batch[r] : -1;
    }

    // ---- GEMM1: h2 = leaky([agg2|h1] @ W2 + brel) ----
    f32x4 acc[2][2] = {};
    {
        const ushort* Wp = W2f + kc * 1024 + t0 * 128 + mr * 8;
#pragma unroll
        for (int kk = 0; kk < 4; ++kk) {           // A = agg2bf (K 0..127)
            short8 bH0 = *(const short8*)(Wp + kk * 8192);
            short8 bH1 = *(const short8*)(Wp + kk * 8192 + 128);
            short8 bL0 = *(const short8*)(Wp + kk * 8192 + 4096);
            short8 bL1 = *(const short8*)(Wp + kk * 8192 + 4096 + 128);
#pragma unroll
            for (int sub = 0; sub < 2; ++sub) {
                int row = i0 + sub * 16 + mr; if (row > n - 1) row = n - 1;
                short8 aH = *(const short8*)(agg2bf + (size_t)row * 128 + kk * 32 + kc * 8);
                MFMA(acc[sub][0], aH, bH0); MFMA(acc[sub][0], aH, bL0);
                MFMA(acc[sub][1], aH, bH1); MFMA(acc[sub][1], aH, bL1);
            }
        }
#pragma unroll
        for (int kk = 4; kk < 8; ++kk) {           // A = h1bf (K 128..255)
            short8 bH0 = *(const short8*)(Wp + kk * 8192);
            short8 bH1 = *(const short8*)(Wp + kk * 8192 + 128);
            short8 bL0 = *(const short8*)(Wp + kk * 8192 + 4096);
            short8 bL1 = *(const short8*)(Wp + kk * 8192 + 4096 + 128);
#pragma unroll
            for (int sub = 0; sub < 2; ++sub) {
                int row = i0 + sub * 16 + mr; if (row > n - 1) row = n - 1;
                short8 aH = *(const short8*)(h1bf + (size_t)row * 128 + (kk - 4) * 32 + kc * 8);
                MFMA(acc[sub][0], aH, bH0); MFMA(acc[sub][0], aH, bL0);
                MFMA(acc[sub][1], aH, bH1); MFMA(acc[sub][1], aH, bL1);
            }
        }
    }

#pragma unroll
    for (int tt = 0; tt < 2; ++tt) {
        int c = (t0 + tt) * 16 + mr;
        float bv = brel[c];
#pragma unroll
        for (int sub = 0; sub < 2; ++sub)
#pragma unroll
            for (int j = 0; j < 4; ++j) {
                int rl = sub * 16 + kc * 4 + j;
                h2s[rl * 132 + c] = LEAKY(acc[sub][tt][j] + bv);
            }
    }
    __syncthreads();

    // ---- GEMM2: gate over [h2|x] ----
    f32x4 as[2][2] = {}, at_[2][2] = {};
    {
        const ushort* Wp = Wgf + kc * 1024 + t0 * 128 + mr * 8;
#pragma unroll
        for (int kk = 0; kk < 4; ++kk) {           // A = LDS h2 f32 (K 0..127)
            short8 sH0 = *(const short8*)(Wp + kk * 16384);
            short8 sH1 = *(const short8*)(Wp + kk * 16384 + 128);
            short8 sL0 = *(const short8*)(Wp + kk * 16384 + 4096);
            short8 sL1 = *(const short8*)(Wp + kk * 16384 + 4096 + 128);
            short8 tH0 = *(const short8*)(Wp + kk * 16384 + 8192);
            short8 tH1 = *(const short8*)(Wp + kk * 16384 + 8192 + 128);
            short8 tL0 = *(const short8*)(Wp + kk * 16384 + 12288);
            short8 tL1 = *(const short8*)(Wp + kk * 16384 + 12288 + 128);
#pragma unroll
            for (int sub = 0; sub < 2; ++sub) {
                short8 aH, aL;
                split8(&h2s[(sub * 16 + mr) * 132 + kk * 32 + kc * 8], aH, aL);
                MFMA(as[sub][0], aH, sH0); MFMA(as[sub][0], aH, sL0); MFMA(as[sub][0], aL, sH0);
                MFMA(as[sub][1], aH, sH1); MFMA(as[sub][1], aH, sL1); MFMA(as[sub][1], aL, sH1);
                MFMA(at_[sub][0], aH, tH0); MFMA(at_[sub][0], aH, tL0); MFMA(at_[sub][0], aL, tH0);
                MFMA(at_[sub][1], aH, tH1); MFMA(at_[sub][1], aH, tL1); MFMA(at_[sub][1], aL, tH1);
            }
        }
#pragma unroll
        for (int kk = 4; kk < 6; ++kk) {           // A = x (K 128..191), exact split
            short8 sH0 = *(const short8*)(Wp + kk * 16384);
            short8 sH1 = *(const short8*)(Wp + kk * 16384 + 128);
            short8 sL0 = *(const short8*)(Wp + kk * 16384 + 4096);
            short8 sL1 = *(const short8*)(Wp + kk * 16384 + 4096 + 128);
            short8 tH0 = *(const short8*)(Wp + kk * 16384 + 8192);
            short8 tH1 = *(const short8*)(Wp + kk * 16384 + 8192 + 128);
            short8 tL0 = *(const short8*)(Wp + kk * 16384 + 12288);
            short8 tL1 = *(const short8*)(Wp + kk * 16384 + 12288 + 128);
#pragma unroll
            for (int sub = 0; sub < 2; ++sub) {
                int row = i0 + sub * 16 + mr; if (row > n - 1) row = n - 1;
                short8 aH, aL;
                split8(x + (size_t)row * 64 + (kk - 4) * 32 + kc * 8, aH, aL);
                MFMA(as[sub][0], aH, sH0); MFMA(as[sub][0], aH, sL0); MFMA(as[sub][0], aL, sH0);
                MFMA(as[sub][1], aH, sH1); MFMA(as[sub][1], aH, sL1); MFMA(as[sub][1], aL, sH1);
                MFMA(at_[sub][0], aH, tH0); MFMA(at_[sub][0], aH, tL0); MFMA(at_[sub][0], aL, tH0);
                MFMA(at_[sub][1], aH, tH1); MFMA(at_[sub][1], aH, tL1); MFMA(at_[sub][1], aL, tH1);
            }
        }
    }
    __syncthreads();   // h2 LDS reads complete -> safe to alias gs

    // ---- gate epilogue ----
#pragma unroll
    for (int tt = 0; tt < 2; ++tt) {
        int c = (t0 + tt) * 16 + mr;
        float bsv = bsig[c], btv = btanh[c];
#pragma unroll
        for (int sub = 0; sub < 2; ++sub)
#pragma unroll
            for (int j = 0; j < 4; ++j) {
                int rl = sub * 16 + kc * 4 + j;
                float s = as[sub][tt][j] + bsv;
                s = fminf(fmaxf(s, -30.f), 30.f);
                float ta = at_[sub][tt][j] + btv;
                ta = fminf(fmaxf(ta, -15.f), 15.f);
                float e2 = __expf(2.f * ta);
                float th = (e2 - 1.f) / (e2 + 1.f);
                gs[rl * 128 + c] = th / (1.f + __expf(s));
            }
    }
    __syncthreads();

    // ---- run-compressed pooling ----
    int j = tid & 127;
    int m0 = (tid >> 7) * 16;
    float acc2 = 0.f;
    int cur = -1;
    for (int m = m0; m < m0 + 16; ++m) {
        int b = bS[m];
        if (b < 0) break;
        if (b != cur) {
            if (cur >= 0) atomicAdd(&pooled[(size_t)cur * 128 + j], acc2);
            cur = b;
            acc2 = 0.f;
        }
        acc2 += gs[m * 128 + j];
    }
    if (cur >= 0) atomicAdd(&pooled[(size_t)cur * 128 + j], acc2);
}

// ---------------------------------------------------------------------------
// Final per-graph MLP
// ---------------------------------------------------------------------------
__global__ __launch_bounds__(256) void mlp_kernel(
    const float* __restrict__ pooled,
    const float* __restrict__ Wf1, const float* __restrict__ bf1,
    const float* __restrict__ Wf2, const float* __restrict__ bf2,
    const float* __restrict__ Wout, const float* __restrict__ bout,
    float* __restrict__ out)
{
    __shared__ float p[128];
    __shared__ float f1[128];
    __shared__ float f2[258];
    __shared__ float red[4];

    int g = blockIdx.x;
    int tid = threadIdx.x;

    if (tid < 128) p[tid] = pooled[(size_t)g * 128 + tid];
    __syncthreads();

    if (tid < 128) {
        float a = bf1[tid];
        for (int k = 0; k < 128; ++k) a += p[k] * Wf1[k * 128 + tid];
        f1[tid] = LEAKY(a);
    }
    __syncthreads();

    for (int j = tid; j < 258; j += 256) {
        float a = bf2[j];
        for (int k = 0; k < 128; ++k) a += f1[k] * Wf2[k * 258 + j];
        f2[j] = LEAKY(a);
    }
    __syncthreads();

    float a = 0.f;
    for (int j = tid; j < 258; j += 256) a += f2[j] * Wout[j];
#pragma unroll
    for (int off = 32; off > 0; off >>= 1) a += __shfl_down(a, off, 64);
    if ((tid & 63) == 0) red[tid >> 6] = a;
    __syncthreads();
    if (tid == 0) {
        float v = red[0] + red[1] + red[2] + red[3] + bout[0];
        out[g] = 1.f / (1.f + expf(-v));
    }
}

// ---------------------------------------------------------------------------
extern "C" void kernel_launch(void* const* d_in, const int* in_sizes, int n_in,
                              void* d_out, int out_size, void* d_ws, size_t ws_size,
                              hipStream_t stream)
{
    const float* x     = (const float*)d_in[0];
    const int*   ei    = (const int*)d_in[1];
    const int*   batch = (const int*)d_in[2];
    const float* ea    = (const float*)d_in[3];
    const float* Wrel1 = (const float*)d_in[4];
    const float* brel1 = (const float*)d_in[5];
    const float* Wroot1= (const float*)d_in[6];
    const float* Wrel2 = (const float*)d_in[7];
    const float* brel2 = (const float*)d_in[8];
    const float* Wroot2= (const float*)d_in[9];
    const float* Wsig  = (const float*)d_in[10];
    const float* bsig  = (const float*)d_in[11];
    const float* Wtanh = (const float*)d_in[12];
    const float* btanh = (const float*)d_in[13];
    const float* Wf1   = (const float*)d_in[14];
    const float* bf1   = (const float*)d_in[15];
    const float* Wf2   = (const float*)d_in[16];
    const float* bf2   = (const float*)d_in[17];
    const float* Wout  = (const float*)d_in[18];
    const float* bout  = (const float*)d_in[19];

    int N = in_sizes[2];
    int E = in_sizes[3];

    char* base = (char*)d_ws;
    size_t off = 0;
    auto alloc = [&](size_t bytes) {
        char* p = base + off;
        off += (bytes + 255) & ~(size_t)255;
        return p;
    };
    ushort*   h1bf  = (ushort*)alloc((size_t)N * 128 * 2);
    ushort*   xbf   = (ushort*)alloc((size_t)N * 64 * 2);
    ushort*   agg1bf= (ushort*)alloc((size_t)N * 64 * 2);
    ushort*   agg2bf= (ushort*)alloc((size_t)N * 128 * 2);
    int*      rowptr= (int*)alloc((size_t)(N + 1) * 4);
    int*      cursor= (int*)alloc((size_t)N * 4);
    int*      bsum  = (int*)alloc(512 * 4);
    int2*     csw   = (int2*)alloc((size_t)E * 8);
    ushort*   W1f   = (ushort*)alloc(32768 * 2);
    ushort*   W2f   = (ushort*)alloc(65536 * 2);
    ushort*   Wgf   = (ushort*)alloc(98304 * 2);
    float*    pooled= (float*)alloc(256 * 128 * 4);

    int eblk = (E + 255) / 256;
    int nblk1 = (N + 1023) / 1024;
    int cblk = (N + 31) / 32;

    hipMemsetAsync(cursor, 0, (size_t)N * sizeof(int), stream);
    hipMemsetAsync(pooled, 0, (size_t)256 * 128 * sizeof(float), stream);

    prep_weights_kernel<<<768, 256, 0, stream>>>(Wrel1, Wroot1, Wrel2, Wroot2,
                                                 Wsig, Wtanh, W1f, W2f, Wgf);
    xbf_kernel<<<(N * 16 + 255) / 256, 256, 0, stream>>>(x, xbf, N * 16);

    // ---- CSR build ----
    hist_kernel<<<eblk, 256, 0, stream>>>(ei, cursor, E);
    scan1_kernel<<<nblk1, 256, 0, stream>>>(cursor, rowptr, bsum, N);
    scan2_kernel<<<1, 512, 0, stream>>>(bsum, nblk1);
    scan3_kernel<<<(N + 255) / 256, 256, 0, stream>>>(rowptr, bsum, N, E);
    hipMemcpyAsync(cursor, rowptr, (size_t)N * sizeof(int),
                   hipMemcpyDeviceToDevice, stream);
    fill_kernel<<<eblk, 256, 0, stream>>>(ei, ea, cursor, csw, E);

    // ---- conv1: gather then GEMM ----
    gather64_kernel<<<(N + 15) / 16, 256, 0, stream>>>(xbf, rowptr, csw,
                                                       agg1bf, N);
    conv1_kernel<<<cblk, 256, 0, stream>>>(x, agg1bf, W1f, brel1, h1bf, N);

    // ---- conv2 + gate + pool: gather then GEMM ----
    gather128_kernel<<<(N + 7) / 8, 256, 0, stream>>>(h1bf, rowptr, csw,
                                                      agg2bf, N);
    conv2_gate_kernel<<<cblk, 256, 0, stream>>>(agg2bf, h1bf, x, W2f, brel2,
                                                Wgf, bsig, btanh, batch,
                                                pooled, N);

    // ---- final MLP ----
    mlp_kernel<<<256, 256, 0, stream>>>(pooled, Wf1, bf1, Wf2, bf2, Wout, bout,
                                        (float*)d_out);
}

// Round 12
// 438.788 us; speedup vs baseline: 1.0012x; 1.0012x over previous
//
#include <hip/hip_runtime.h>
#include <cstdint>

#define RELU_COEF 0.05f
#define LEAKY(v) ((v) > 0.f ? (v) : RELU_COEF * (v))

typedef __attribute__((ext_vector_type(8))) short short8;
typedef __attribute__((ext_vector_type(4))) float f32x4;

#define MFMA(acc, a, b) \
    acc = __builtin_amdgcn_mfma_f32_16x16x32_bf16(a, b, acc, 0, 0, 0)

__device__ inline ushort f2bf(float f) {
    union { float f; uint32_t u; } v; v.f = f;
    return (ushort)((v.u + 0x7FFFu + ((v.u >> 16) & 1u)) >> 16);
}
__device__ inline float bf2f(ushort h) {
    union { uint32_t u; float f; } v; v.u = ((uint32_t)h) << 16;
    return v.f;
}
__device__ inline void split8(const float* p, short8& h8, short8& l8) {
    float4 a = *(const float4*)p;
    float4 b = *(const float4*)(p + 4);
    float v[8] = {a.x, a.y, a.z, a.w, b.x, b.y, b.z, b.w};
    short8 hh, ll;
#pragma unroll
    for (int i = 0; i < 8; ++i) {
        ushort hi = f2bf(v[i]);
        hh[i] = (short)hi;
        ll[i] = (short)f2bf(v[i] - bf2f(hi));
    }
    h8 = hh; l8 = ll;
}

// ---------------------------------------------------------------------------
// CSR build
// ---------------------------------------------------------------------------
__global__ __launch_bounds__(256) void hist_kernel(
    const int* __restrict__ ei, int* __restrict__ deg, int E)
{
    int e = blockIdx.x * 256 + threadIdx.x;
    if (e >= E) return;
    atomicAdd(&deg[ei[(size_t)E + e]], 1);
}

__global__ __launch_bounds__(256) void scan1_kernel(
    const int* __restrict__ in, int* __restrict__ out, int* __restrict__ bsum, int N)
{
    __shared__ int ts[256];
    int tid = threadIdx.x;
    int base = blockIdx.x * 1024 + tid * 4;
    int v[4];
    int s = 0;
#pragma unroll
    for (int j = 0; j < 4; ++j) {
        int idx = base + j;
        v[j] = (idx < N) ? in[idx] : 0;
        s += v[j];
    }
    ts[tid] = s;
    __syncthreads();
    for (int off = 1; off < 256; off <<= 1) {
        int t = (tid >= off) ? ts[tid - off] : 0;
        __syncthreads();
        ts[tid] += t;
        __syncthreads();
    }
    int excl = ts[tid] - s;
    if (tid == 255) bsum[blockIdx.x] = ts[255];
    int run = excl;
#pragma unroll
    for (int j = 0; j < 4; ++j) {
        int idx = base + j;
        if (idx < N) out[idx] = run;
        run += v[j];
    }
}

__global__ __launch_bounds__(512) void scan2_kernel(int* bsum, int nb)
{
    __shared__ int ts[512];
    int tid = threadIdx.x;
    int v = (tid < nb) ? bsum[tid] : 0;
    ts[tid] = v;
    __syncthreads();
    for (int off = 1; off < 512; off <<= 1) {
        int t = (tid >= off) ? ts[tid - off] : 0;
        __syncthreads();
        ts[tid] += t;
        __syncthreads();
    }
    if (tid < nb) bsum[tid] = ts[tid] - v;
}

__global__ __launch_bounds__(256) void scan3_kernel(
    int* __restrict__ rowptr, const int* __restrict__ bsum, int N, int E)
{
    int idx = blockIdx.x * 256 + threadIdx.x;
    if (idx < N) rowptr[idx] += bsum[idx >> 10];
    if (idx == 0) rowptr[N] = E;
}

// fill: single 8B packed store per edge (src idx, fp32 weight)
__global__ __launch_bounds__(256) void fill_kernel(
    const int* __restrict__ ei, const float* __restrict__ ea,
    int* __restrict__ cursor, int2* __restrict__ csw, int E)
{
    int e = blockIdx.x * 256 + threadIdx.x;
    if (e >= E) return;
    int t = ei[(size_t)E + e];
    int pos = atomicAdd(&cursor[t], 1);
    csw[pos] = make_int2(ei[e], __float_as_int(ea[e]));
}

// ---------------------------------------------------------------------------
// x -> bf16 copy (gather payload for conv1)
// ---------------------------------------------------------------------------
__global__ __launch_bounds__(256) void xbf_kernel(
    const float* __restrict__ x, ushort* __restrict__ xbf, int total4)
{
    int i = blockIdx.x * 256 + threadIdx.x;
    if (i >= total4) return;
    float4 v = *(const float4*)(x + (size_t)i * 4);
    ushort4 h;
    h.x = f2bf(v.x); h.y = f2bf(v.y); h.z = f2bf(v.z); h.w = f2bf(v.w);
    *(ushort4*)(xbf + (size_t)i * 4) = h;
}

// ---------------------------------------------------------------------------
// Weight prep -> fragment-major split-bf16 layouts (coalesced B loads):
// W1f[kk:4][hl:2][kc:4][n:128][e:8]   (K=128: agg1|x)
// W2f[kk:8][hl:2][kc:4][n:128][e:8]   (K=256: agg2|h1)
// Wgf[kk:6][p:4 (sH,sL,tH,tL)][kc:4][n:128][e:8]  (K=192: h2|x)
// ---------------------------------------------------------------------------
__global__ __launch_bounds__(256) void prep_weights_kernel(
    const float* __restrict__ Wrel1, const float* __restrict__ Wroot1,
    const float* __restrict__ Wrel2, const float* __restrict__ Wroot2,
    const float* __restrict__ Wsig, const float* __restrict__ Wtanh,
    ushort* __restrict__ W1f, ushort* __restrict__ W2f, ushort* __restrict__ Wgf)
{
    int gid = blockIdx.x * 256 + threadIdx.x;
    if (gid < 32768) {
        int e = gid & 7, nn = (gid >> 3) & 127, kc = (gid >> 10) & 3;
        int hl = (gid >> 12) & 1, kk = gid >> 13;
        int k = kk * 32 + kc * 8 + e;
        float v = (k < 64) ? Wrel1[(size_t)k * 128 + nn]
                           : Wroot1[(size_t)(k - 64) * 128 + nn];
        ushort hi = f2bf(v);
        W1f[gid] = hl ? f2bf(v - bf2f(hi)) : hi;
        return;
    }
    int g2 = gid - 32768;
    if (g2 < 65536) {
        int e = g2 & 7, nn = (g2 >> 3) & 127, kc = (g2 >> 10) & 3;
        int hl = (g2 >> 12) & 1, kk = g2 >> 13;
        int k = kk * 32 + kc * 8 + e;
        float v = (k < 128) ? Wrel2[(size_t)k * 128 + nn]
                            : Wroot2[(size_t)(k - 128) * 128 + nn];
        ushort hi = f2bf(v);
        W2f[g2] = hl ? f2bf(v - bf2f(hi)) : hi;
        return;
    }
    int g3 = g2 - 65536;
    if (g3 < 98304) {
        int e = g3 & 7, nn = (g3 >> 3) & 127, kc = (g3 >> 10) & 3;
        int p = (g3 >> 12) & 3, kk = g3 >> 14;
        int k = kk * 32 + kc * 8 + e;
        float v = (p < 2) ? Wsig[(size_t)k * 128 + nn]
                          : Wtanh[(size_t)k * 128 + nn];
        ushort hi = f2bf(v);
        Wgf[g3] = (p & 1) ? f2bf(v - bf2f(hi)) : hi;
    }
}

// ---------------------------------------------------------------------------
// Standalone gather (conv1): agg1bf[node] = bf16( sum w * xbf[src] )
// 16 lanes/node, shfl-broadcast packed (idx,w), 8-deep loads. No LDS.
// ---------------------------------------------------------------------------
__global__ __launch_bounds__(256) void gather64_kernel(
    const ushort* __restrict__ xbf, const int* __restrict__ rowptr,
    const int2* __restrict__ csw, ushort* __restrict__ agg1bf, int N)
{
    int q = threadIdx.x & 15;
    int node = blockIdx.x * 16 + (threadIdx.x >> 4);
    if (node >= N) return;
    float ax = 0.f, ay = 0.f, az = 0.f, aw = 0.f;
    int b = rowptr[node], e = rowptr[node + 1];
    for (int cb = b; cb < e; cb += 16) {
        int cnt = e - cb; if (cnt > 16) cnt = 16;
        int sIdx = 0; float sW = 0.f;
        if (q < cnt) {
            int2 p = csw[cb + q];
            sIdx = p.x; sW = __int_as_float(p.y);
        }
        int j = 0;
        for (; j + 8 <= cnt; j += 8) {
            int si[8]; float wi[8]; ushort4 fv[8];
#pragma unroll
            for (int u = 0; u < 8; ++u) {
                si[u] = __shfl(sIdx, j + u, 16);
                wi[u] = __shfl(sW, j + u, 16);
            }
#pragma unroll
            for (int u = 0; u < 8; ++u)
                fv[u] = *(const ushort4*)(xbf + (size_t)si[u] * 64 + q * 4);
#pragma unroll
            for (int u = 0; u < 8; ++u) {
                ax += wi[u] * bf2f(fv[u].x);
                ay += wi[u] * bf2f(fv[u].y);
                az += wi[u] * bf2f(fv[u].z);
                aw += wi[u] * bf2f(fv[u].w);
            }
        }
        for (; j < cnt; ++j) {
            int s0 = __shfl(sIdx, j, 16); float w0 = __shfl(sW, j, 16);
            ushort4 f0 = *(const ushort4*)(xbf + (size_t)s0 * 64 + q * 4);
            ax += w0 * bf2f(f0.x); ay += w0 * bf2f(f0.y);
            az += w0 * bf2f(f0.z); aw += w0 * bf2f(f0.w);
        }
    }
    ushort4 h;
    h.x = f2bf(ax); h.y = f2bf(ay); h.z = f2bf(az); h.w = f2bf(aw);
    *(ushort4*)(agg1bf + (size_t)node * 64 + q * 4) = h;
}

// ---------------------------------------------------------------------------
// Standalone gather (conv2): agg2bf[node] = bf16( sum w * h1bf[src] )
// 32 lanes/node. No LDS, no barriers -> minimal VGPR, max occupancy.
// ---------------------------------------------------------------------------
__global__ __launch_bounds__(256) void gather128_kernel(
    const ushort* __restrict__ h1bf, const int* __restrict__ rowptr,
    const int2* __restrict__ csw, ushort* __restrict__ agg2bf, int N)
{
    int q = threadIdx.x & 31;
    int node = blockIdx.x * 8 + (threadIdx.x >> 5);
    if (node >= N) return;
    float ax = 0.f, ay = 0.f, az = 0.f, aw = 0.f;
    int b = rowptr[node], e = rowptr[node + 1];
    for (int cb = b; cb < e; cb += 32) {
        int cnt = e - cb; if (cnt > 32) cnt = 32;
        int sIdx = 0; float sW = 0.f;
        if (q < cnt) {
            int2 p = csw[cb + q];
            sIdx = p.x; sW = __int_as_float(p.y);
        }
        int j = 0;
        for (; j + 8 <= cnt; j += 8) {
            int si[8]; float wi[8]; ushort4 fv[8];
#pragma unroll
            for (int u = 0; u < 8; ++u) {
                si[u] = __shfl(sIdx, j + u, 32);
                wi[u] = __shfl(sW, j + u, 32);
            }
#pragma unroll
            for (int u = 0; u < 8; ++u)
                fv[u] = *(const ushort4*)(h1bf + (size_t)si[u] * 128 + q * 4);
#pragma unroll
            for (int u = 0; u < 8; ++u) {
                ax += wi[u] * bf2f(fv[u].x);
                ay += wi[u] * bf2f(fv[u].y);
                az += wi[u] * bf2f(fv[u].z);
                aw += wi[u] * bf2f(fv[u].w);
            }
        }
        for (; j < cnt; ++j) {
            int s0 = __shfl(sIdx, j, 32); float w0 = __shfl(sW, j, 32);
            ushort4 f0 = *(const ushort4*)(h1bf + (size_t)s0 * 128 + q * 4);
            ax += w0 * bf2f(f0.x); ay += w0 * bf2f(f0.y);
            az += w0 * bf2f(f0.z); aw += w0 * bf2f(f0.w);
        }
    }
    ushort4 h;
    h.x = f2bf(ax); h.y = f2bf(ay); h.z = f2bf(az); h.w = f2bf(aw);
    *(ushort4*)(agg2bf + (size_t)node * 128 + q * 4) = h;
}

// ---------------------------------------------------------------------------
// conv1 GEMM (streaming, no LDS/barriers): h1bf = bf16(leaky([agg1|x]@W1+b))
// ---------------------------------------------------------------------------
__global__ __launch_bounds__(256) void conv1_kernel(
    const float* __restrict__ x, const ushort* __restrict__ agg1bf,
    const ushort* __restrict__ W1f, const float* __restrict__ brel,
    ushort* __restrict__ h1bf, int n)
{
    int tid = threadIdx.x;
    int lane = tid & 63;
    int wv = tid >> 6;
    int mr = lane & 15;
    int kc = lane >> 4;
    int i0 = blockIdx.x * 32;
    int t0 = wv * 2;
    const ushort* Wp = W1f + kc * 1024 + t0 * 128 + mr * 8;
    f32x4 acc[2][2] = {};

#pragma unroll
    for (int kk = 0; kk < 2; ++kk) {      // A = agg1bf (K 0..63), bf16 direct
        short8 bH0 = *(const short8*)(Wp + kk * 8192);
        short8 bH1 = *(const short8*)(Wp + kk * 8192 + 128);
        short8 bL0 = *(const short8*)(Wp + kk * 8192 + 4096);
        short8 bL1 = *(const short8*)(Wp + kk * 8192 + 4096 + 128);
#pragma unroll
        for (int sub = 0; sub < 2; ++sub) {
            int row = i0 + sub * 16 + mr; if (row > n - 1) row = n - 1;
            short8 aH = *(const short8*)(agg1bf + (size_t)row * 64 + kk * 32 + kc * 8);
            MFMA(acc[sub][0], aH, bH0); MFMA(acc[sub][0], aH, bL0);
            MFMA(acc[sub][1], aH, bH1); MFMA(acc[sub][1], aH, bL1);
        }
    }
#pragma unroll
    for (int kk = 2; kk < 4; ++kk) {      // A = x (K 64..127), exact split
        short8 bH0 = *(const short8*)(Wp + kk * 8192);
        short8 bH1 = *(const short8*)(Wp + kk * 8192 + 128);
        short8 bL0 = *(const short8*)(Wp + kk * 8192 + 4096);
        short8 bL1 = *(const short8*)(Wp + kk * 8192 + 4096 + 128);
#pragma unroll
        for (int sub = 0; sub < 2; ++sub) {
            int row = i0 + sub * 16 + mr; if (row > n - 1) row = n - 1;
            short8 aH, aL;
            split8(x + (size_t)row * 64 + (kk - 2) * 32 + kc * 8, aH, aL);
            MFMA(acc[sub][0], aH, bH0); MFMA(acc[sub][0], aH, bL0); MFMA(acc[sub][0], aL, bH0);
            MFMA(acc[sub][1], aH, bH1); MFMA(acc[sub][1], aH, bL1); MFMA(acc[sub][1], aL, bH1);
        }
    }

#pragma unroll
    for (int tt = 0; tt < 2; ++tt) {
        int c = (t0 + tt) * 16 + mr;
        float bv = brel[c];
#pragma unroll
        for (int sub = 0; sub < 2; ++sub)
#pragma unroll
            for (int j = 0; j < 4; ++j) {
                int r = i0 + sub * 16 + kc * 4 + j;
                if (r < n)
                    h1bf[(size_t)r * 128 + c] = f2bf(LEAKY(acc[sub][tt][j] + bv));
            }
    }
}

// ---------------------------------------------------------------------------
// conv2 + gate + pool GEMM (streaming): reads agg2bf/h1bf/x, h2 in LDS,
// gate epilogue, run-compressed pooling.
// ---------------------------------------------------------------------------
__global__ __launch_bounds__(256) void conv2_gate_kernel(
    const ushort* __restrict__ agg2bf, const ushort* __restrict__ h1bf,
    const float* __restrict__ x,
    const ushort* __restrict__ W2f, const float* __restrict__ brel,
    const ushort* __restrict__ Wgf, const float* __restrict__ bsig,
    const float* __restrict__ btanh, const int* __restrict__ batch,
    float* __restrict__ pooled, int n)
{
    __shared__ __align__(16) float h2s[32 * 132];   // 16896 B: h2 -> gs
    __shared__ int bS[32];
    float* gs = h2s;                                 // alias (stride 128)

    int tid = threadIdx.x;
    int lane = tid & 63;
    int wv = tid >> 6;
    int mr = lane & 15;
    int kc = lane >> 4;
    int i0 = blockIdx.x * 32;
    int t0 = wv * 2;

    if (tid < 32) {
        int r = i0 + tid;
        bS[tid] = (r < n) ? batch[r] : -1;
    }

    // ---- GEMM1: h2 = leaky([agg2|h1] @ W2 + brel) ----
    f32x4 acc[2][2] = {};
    {
        const ushort* Wp = W2f + kc * 1024 + t0 * 128 + mr * 8;
#pragma unroll
        for (int kk = 0; kk < 4; ++kk) {           // A = agg2bf (K 0..127)
            short8 bH0 = *(const short8*)(Wp + kk * 8192);
            short8 bH1 = *(const short8*)(Wp + kk * 8192 + 128);
            short8 bL0 = *(const short8*)(Wp + kk * 8192 + 4096);
            short8 bL1 = *(const short8*)(Wp + kk * 8192 + 4096 + 128);
#pragma unroll
            for (int sub = 0; sub < 2; ++sub) {
                int row = i0 + sub * 16 + mr; if (row > n - 1) row = n - 1;
                short8 aH = *(const short8*)(agg2bf + (size_t)row * 128 + kk * 32 + kc * 8);
                MFMA(acc[sub][0], aH, bH0); MFMA(acc[sub][0], aH, bL0);
                MFMA(acc[sub][1], aH, bH1); MFMA(acc[sub][1], aH, bL1);
            }
        }
#pragma unroll
        for (int kk = 4; kk < 8; ++kk) {           // A = h1bf (K 128..255)
            short8 bH0 = *(const short8*)(Wp + kk * 8192);
            short8 bH1 = *(const short8*)(Wp + kk * 8192 + 128);
            short8 bL0 = *(const short8*)(Wp + kk * 8192 + 4096);
            short8 bL1 = *(const short8*)(Wp + kk * 8192 + 4096 + 128);
#pragma unroll
            for (int sub = 0; sub < 2; ++sub) {
                int row = i0 + sub * 16 + mr; if (row > n - 1) row = n - 1;
                short8 aH = *(const short8*)(h1bf + (size_t)row * 128 + (kk - 4) * 32 + kc * 8);
                MFMA(acc[sub][0], aH, bH0); MFMA(acc[sub][0], aH, bL0);
                MFMA(acc[sub][1], aH, bH1); MFMA(acc[sub][1], aH, bL1);
            }
        }
    }

#pragma unroll
    for (int tt = 0; tt < 2; ++tt) {
        int c = (t0 + tt) * 16 + mr;
        float bv = brel[c];
#pragma unroll
        for (int sub = 0; sub < 2; ++sub)
#pragma unroll
            for (int j = 0; j < 4; ++j) {
                int rl = sub * 16 + kc * 4 + j;
                h2s[rl * 132 + c] = LEAKY(acc[sub][tt][j] + bv);
            }
    }
    __syncthreads();

    // ---- GEMM2: gate over [h2|x] ----
    f32x4 as[2][2] = {}, at_[2][2] = {};
    {
        const ushort* Wp = Wgf + kc * 1024 + t0 * 128 + mr * 8;
#pragma unroll
        for (int kk = 0; kk < 4; ++kk) {           // A = LDS h2 f32 (K 0..127)
            short8 sH0 = *(const short8*)(Wp + kk * 16384);
            short8 sH1 = *(const short8*)(Wp + kk * 16384 + 128);
            short8 sL0 = *(const short8*)(Wp + kk * 16384 + 4096);
            short8 sL1 = *(const short8*)(Wp + kk * 16384 + 4096 + 128);
            short8 tH0 = *(const short8*)(Wp + kk * 16384 + 8192);
            short8 tH1 = *(const short8*)(Wp + kk * 16384 + 8192 + 128);
            short8 tL0 = *(const short8*)(Wp + kk * 16384 + 12288);
            short8 tL1 = *(const short8*)(Wp + kk * 16384 + 12288 + 128);
#pragma unroll
            for (int sub = 0; sub < 2; ++sub) {
                short8 aH, aL;
                split8(&h2s[(sub * 16 + mr) * 132 + kk * 32 + kc * 8], aH, aL);
                MFMA(as[sub][0], aH, sH0); MFMA(as[sub][0], aH, sL0); MFMA(as[sub][0], aL, sH0);
                MFMA(as[sub][1], aH, sH1); MFMA(as[sub][1], aH, sL1); MFMA(as[sub][1], aL, sH1);
                MFMA(at_[sub][0], aH, tH0); MFMA(at_[sub][0], aH, tL0); MFMA(at_[sub][0], aL, tH0);
                MFMA(at_[sub][1], aH, tH1); MFMA(at_[sub][1], aH, tL1); MFMA(at_[sub][1], aL, tH1);
            }
        }
#pragma unroll
        for (int kk = 4; kk < 6; ++kk) {           // A = x (K 128..191), exact split
            short8 sH0 = *(const short8*)(Wp + kk * 16384);
            short8 sH1 = *(const short8*)(Wp + kk * 16384 + 128);
            short8 sL0 = *(const short8*)(Wp + kk * 16384 + 4096);
            short8 sL1 = *(const short8*)(Wp + kk * 16384 + 4096 + 128);
            short8 tH0 = *(const short8*)(Wp + kk * 16384 + 8192);
            short8 tH1 = *(const short8*)(Wp + kk * 16384 + 8192 + 128);
            short8 tL0 = *(const short8*)(Wp + kk * 16384 + 12288);
            short8 tL1 = *(const short8*)(Wp + kk * 16384 + 12288 + 128);
#pragma unroll
            for (int sub = 0; sub < 2; ++sub) {
                int row = i0 + sub * 16 + mr; if (row > n - 1) row = n - 1;
                short8 aH, aL;
                split8(x + (size_t)row * 64 + (kk - 4) * 32 + kc * 8, aH, aL);
                MFMA(as[sub][0], aH, sH0); MFMA(as[sub][0], aH, sL0); MFMA(as[sub][0], aL, sH0);
                MFMA(as[sub][1], aH, sH1); MFMA(as[sub][1], aH, sL1); MFMA(as[sub][1], aL, sH1);
                MFMA(at_[sub][0], aH, tH0); MFMA(at_[sub][0], aH, tL0); MFMA(at_[sub][0], aL, tH0);
                MFMA(at_[sub][1], aH, tH1); MFMA(at_[sub][1], aH, tL1); MFMA(at_[sub][1], aL, tH1);
            }
        }
    }
    __syncthreads();   // h2 LDS reads complete -> safe to alias gs

    // ---- gate epilogue ----
#pragma unroll
    for (int tt = 0; tt < 2; ++tt) {
        int c = (t0 + tt) * 16 + mr;
        float bsv = bsig[c], btv = btanh[c];
#pragma unroll
        for (int sub = 0; sub < 2; ++sub)
#pragma unroll
            for (int j = 0; j < 4; ++j) {
                int rl = sub * 16 + kc * 4 + j;
                float s = as[sub][tt][j] + bsv;
                s = fminf(fmaxf(s, -30.f), 30.f);
                float ta = at_[sub][tt][j] + btv;
                ta = fminf(fmaxf(ta, -15.f), 15.f);
                float e2 = __expf(2.f * ta);
                float th = (e2 - 1.f) / (e2 + 1.f);
                gs[rl * 128 + c] = th / (1.f + __expf(s));
            }
    }
    __syncthreads();

    // ---- run-compressed pooling ----
    int j = tid & 127;
    int m0 = (tid >> 7) * 16;
    float acc2 = 0.f;
    int cur = -1;
    for (int m = m0; m < m0 + 16; ++m) {
        int b = bS[m];
        if (b < 0) break;
        if (b != cur) {
            if (cur >= 0) atomicAdd(&pooled[(size_t)cur * 128 + j], acc2);
            cur = b;
            acc2 = 0.f;
        }
        acc2 += gs[m * 128 + j];
    }
    if (cur >= 0) atomicAdd(&pooled[(size_t)cur * 128 + j], acc2);
}

// ---------------------------------------------------------------------------
// Final per-graph MLP
// ---------------------------------------------------------------------------
__global__ __launch_bounds__(256) void mlp_kernel(
    const float* __restrict__ pooled,
    const float* __restrict__ Wf1, const float* __restrict__ bf1,
    const float* __restrict__ Wf2, const float* __restrict__ bf2,
    const float* __restrict__ Wout, const float* __restrict__ bout,
    float* __restrict__ out)
{
    __shared__ float p[128];
    __shared__ float f1[128];
    __shared__ float f2[258];
    __shared__ float red[4];

    int g = blockIdx.x;
    int tid = threadIdx.x;

    if (tid < 128) p[tid] = pooled[(size_t)g * 128 + tid];
    __syncthreads();

    if (tid < 128) {
        float a = bf1[tid];
        for (int k = 0; k < 128; ++k) a += p[k] * Wf1[k * 128 + tid];
        f1[tid] = LEAKY(a);
    }
    __syncthreads();

    for (int j = tid; j < 258; j += 256) {
        float a = bf2[j];
        for (int k = 0; k < 128; ++k) a += f1[k] * Wf2[k * 258 + j];
        f2[j] = LEAKY(a);
    }
    __syncthreads();

    float a = 0.f;
    for (int j = tid; j < 258; j += 256) a += f2[j] * Wout[j];
#pragma unroll
    for (int off = 32; off > 0; off >>= 1) a += __shfl_down(a, off, 64);
    if ((tid & 63) == 0) red[tid >> 6] = a;
    __syncthreads();
    if (tid == 0) {
        float v = red[0] + red[1] + red[2] + red[3] + bout[0];
        out[g] = 1.f / (1.f + expf(-v));
    }
}

// ---------------------------------------------------------------------------
extern "C" void kernel_launch(void* const* d_in, const int* in_sizes, int n_in,
                              void* d_out, int out_size, void* d_ws, size_t ws_size,
                              hipStream_t stream)
{
    const float* x     = (const float*)d_in[0];
    const int*   ei    = (const int*)d_in[1];
    const int*   batch = (const int*)d_in[2];
    const float* ea    = (const float*)d_in[3];
    const float* Wrel1 = (const float*)d_in[4];
    const float* brel1 = (const float*)d_in[5];
    const float* Wroot1= (const float*)d_in[6];
    const float* Wrel2 = (const float*)d_in[7];
    const float* brel2 = (const float*)d_in[8];
    const float* Wroot2= (const float*)d_in[9];
    const float* Wsig  = (const float*)d_in[10];
    const float* bsig  = (const float*)d_in[11];
    const float* Wtanh = (const float*)d_in[12];
    const float* btanh = (const float*)d_in[13];
    const float* Wf1   = (const float*)d_in[14];
    const float* bf1   = (const float*)d_in[15];
    const float* Wf2   = (const float*)d_in[16];
    const float* bf2   = (const float*)d_in[17];
    const float* Wout  = (const float*)d_in[18];
    const float* bout  = (const float*)d_in[19];

    int N = in_sizes[2];
    int E = in_sizes[3];

    char* base = (char*)d_ws;
    size_t off = 0;
    auto alloc = [&](size_t bytes) {
        char* p = base + off;
        off += (bytes + 255) & ~(size_t)255;
        return p;
    };
    ushort*   h1bf  = (ushort*)alloc((size_t)N * 128 * 2);
    ushort*   xbf   = (ushort*)alloc((size_t)N * 64 * 2);
    ushort*   agg1bf= (ushort*)alloc((size_t)N * 64 * 2);
    ushort*   agg2bf= (ushort*)alloc((size_t)N * 128 * 2);
    int*      rowptr= (int*)alloc((size_t)(N + 1) * 4);
    int*      cursor= (int*)alloc((size_t)N * 4);
    int*      bsum  = (int*)alloc(512 * 4);
    int2*     csw   = (int2*)alloc((size_t)E * 8);
    ushort*   W1f   = (ushort*)alloc(32768 * 2);
    ushort*   W2f   = (ushort*)alloc(65536 * 2);
    ushort*   Wgf   = (ushort*)alloc(98304 * 2);
    float*    pooled= (float*)alloc(256 * 128 * 4);

    int eblk = (E + 255) / 256;
    int nblk1 = (N + 1023) / 1024;
    int cblk = (N + 31) / 32;

    hipMemsetAsync(cursor, 0, (size_t)N * sizeof(int), stream);
    hipMemsetAsync(pooled, 0, (size_t)256 * 128 * sizeof(float), stream);

    prep_weights_kernel<<<768, 256, 0, stream>>>(Wrel1, Wroot1, Wrel2, Wroot2,
                                                 Wsig, Wtanh, W1f, W2f, Wgf);
    xbf_kernel<<<(N * 16 + 255) / 256, 256, 0, stream>>>(x, xbf, N * 16);

    // ---- CSR build ----
    hist_kernel<<<eblk, 256, 0, stream>>>(ei, cursor, E);
    scan1_kernel<<<nblk1, 256, 0, stream>>>(cursor, rowptr, bsum, N);
    scan2_kernel<<<1, 512, 0, stream>>>(bsum, nblk1);
    scan3_kernel<<<(N + 255) / 256, 256, 0, stream>>>(rowptr, bsum, N, E);
    hipMemcpyAsync(cursor, rowptr, (size_t)N * sizeof(int),
                   hipMemcpyDeviceToDevice, stream);
    fill_kernel<<<eblk, 256, 0, stream>>>(ei, ea, cursor, csw, E);

    // ---- conv1: gather then GEMM ----
    gather64_kernel<<<(N + 15) / 16, 256, 0, stream>>>(xbf, rowptr, csw,
                                                       agg1bf, N);
    conv1_kernel<<<cblk, 256, 0, stream>>>(x, agg1bf, W1f, brel1, h1bf, N);

    // ---- conv2 + gate + pool: gather then GEMM ----
    gather128_kernel<<<(N + 7) / 8, 256, 0, stream>>>(h1bf, rowptr, csw,
                                                      agg2bf, N);
    conv2_gate_kernel<<<cblk, 256, 0, stream>>>(agg2bf, h1bf, x, W2f, brel2,
                                                Wgf, bsig, btanh, batch,
                                                pooled, N);

    // ---- final MLP ----
    mlp_kernel<<<256, 256, 0, stream>>>(pooled, Wf1, bf1, Wf2, bf2, Wout, bout,
                                        (float*)d_out);
}

// Round 13
// 355.894 us; speedup vs baseline: 1.2344x; 1.2329x over previous
//
#include <hip/hip_runtime.h>
#include <cstdint>

#define RELU_COEF 0.05f
#define LEAKY(v) ((v) > 0.f ? (v) : RELU_COEF * (v))

typedef __attribute__((ext_vector_type(8))) short short8;
typedef __attribute__((ext_vector_type(4))) float f32x4;

#define MFMA(acc, a, b) \
    acc = __builtin_amdgcn_mfma_f32_16x16x32_bf16(a, b, acc, 0, 0, 0)

__device__ inline ushort f2bf(float f) {
    union { float f; uint32_t u; } v; v.f = f;
    return (ushort)((v.u + 0x7FFFu + ((v.u >> 16) & 1u)) >> 16);
}
__device__ inline float bf2f(ushort h) {
    union { uint32_t u; float f; } v; v.u = ((uint32_t)h) << 16;
    return v.f;
}
__device__ inline void split8(const float* p, short8& h8, short8& l8) {
    float4 a = *(const float4*)p;
    float4 b = *(const float4*)(p + 4);
    float v[8] = {a.x, a.y, a.z, a.w, b.x, b.y, b.z, b.w};
    short8 hh, ll;
#pragma unroll
    for (int i = 0; i < 8; ++i) {
        ushort hi = f2bf(v[i]);
        hh[i] = (short)hi;
        ll[i] = (short)f2bf(v[i] - bf2f(hi));
    }
    h8 = hh; l8 = ll;
}

// ---------------------------------------------------------------------------
// CSR build: hist -> scan -> two-pass bucketed partition (locality-aware)
// Assumes N <= 131072 (src fits 17 bits, bucket = dst>>9 fits 8 bits).
// ---------------------------------------------------------------------------
__global__ __launch_bounds__(256) void hist_kernel(
    const int* __restrict__ ei, int* __restrict__ deg, int E)
{
    int e = blockIdx.x * 256 + threadIdx.x;
    if (e >= E) return;
    atomicAdd(&deg[ei[(size_t)E + e]], 1);
}

__global__ __launch_bounds__(256) void scan1_kernel(
    const int* __restrict__ in, int* __restrict__ out, int* __restrict__ bsum, int N)
{
    __shared__ int ts[256];
    int tid = threadIdx.x;
    int base = blockIdx.x * 1024 + tid * 4;
    int v[4];
    int s = 0;
#pragma unroll
    for (int j = 0; j < 4; ++j) {
        int idx = base + j;
        v[j] = (idx < N) ? in[idx] : 0;
        s += v[j];
    }
    ts[tid] = s;
    __syncthreads();
    for (int off = 1; off < 256; off <<= 1) {
        int t = (tid >= off) ? ts[tid - off] : 0;
        __syncthreads();
        ts[tid] += t;
        __syncthreads();
    }
    int excl = ts[tid] - s;
    if (tid == 255) bsum[blockIdx.x] = ts[255];
    int run = excl;
#pragma unroll
    for (int j = 0; j < 4; ++j) {
        int idx = base + j;
        if (idx < N) out[idx] = run;
        run += v[j];
    }
}

__global__ __launch_bounds__(512) void scan2_kernel(int* bsum, int nb)
{
    __shared__ int ts[512];
    int tid = threadIdx.x;
    int v = (tid < nb) ? bsum[tid] : 0;
    ts[tid] = v;
    __syncthreads();
    for (int off = 1; off < 512; off <<= 1) {
        int t = (tid >= off) ? ts[tid - off] : 0;
        __syncthreads();
        ts[tid] += t;
        __syncthreads();
    }
    if (tid < nb) bsum[tid] = ts[tid] - v;
}

__global__ __launch_bounds__(256) void scan3_kernel(
    int* __restrict__ rowptr, const int* __restrict__ bsum, int N, int E)
{
    int idx = blockIdx.x * 256 + threadIdx.x;
    if (idx < N) rowptr[idx] += bsum[idx >> 10];
    if (idx == 0) rowptr[N] = E;
}

// Pass A: partition edges into 512-node buckets with run-coalesced writes.
#define CHUNK 4096
__global__ __launch_bounds__(256) void partA_kernel(
    const int* __restrict__ ei, const float* __restrict__ ea,
    const int* __restrict__ rowptr, int* __restrict__ bucketCursor,
    int2* __restrict__ csw2, int E, int NB)
{
    __shared__ int cnt[256];
    __shared__ int scanx[256];
    __shared__ int runc[256];
    __shared__ int gbase[256];
    __shared__ int2 staged[CHUNK];
    __shared__ unsigned char bkt[CHUNK];

    int tid = threadIdx.x;
    long long base = (long long)blockIdx.x * CHUNK;
    int cntHere = (int)((E - base) < CHUNK ? (E - base) : CHUNK);

    cnt[tid] = 0; runc[tid] = 0;
    __syncthreads();

    // phase 1: histogram
    for (int i = tid; i < cntHere; i += 256) {
        int d = ei[(size_t)E + base + i];
        atomicAdd(&cnt[d >> 9], 1);
    }
    __syncthreads();

    // exclusive scan over 256 buckets
    int v = cnt[tid];
    scanx[tid] = v;
    __syncthreads();
    for (int off = 1; off < 256; off <<= 1) {
        int t = (tid >= off) ? scanx[tid - off] : 0;
        __syncthreads();
        scanx[tid] += t;
        __syncthreads();
    }
    int excl = scanx[tid] - v;
    if (tid < NB && v > 0)
        gbase[tid] = rowptr[tid << 9] + atomicAdd(&bucketCursor[tid], v);
    scanx[tid] = excl;
    __syncthreads();

    // phase 2: scatter into LDS, bucket-ordered
    for (int i = tid; i < cntHere; i += 256) {
        long long e = base + i;
        int d = ei[(size_t)E + e];
        int b = d >> 9;
        int idx = scanx[b] + atomicAdd(&runc[b], 1);
        staged[idx] = make_int2(((d & 511) << 17) | ei[e], __float_as_int(ea[e]));
        bkt[idx] = (unsigned char)b;
    }
    __syncthreads();

    // phase 3: run-contiguous write-out
    for (int i = tid; i < cntHere; i += 256) {
        int b = bkt[i];
        csw2[gbase[b] + (i - scanx[b])] = staged[i];
    }
}

// Pass B: exact within-bucket CSR sort; one workgroup per bucket so all
// stores to the bucket's CSR window come from one XCD (lines fully dirtied).
__global__ __launch_bounds__(256) void partB_kernel(
    const int2* __restrict__ csw2, const int* __restrict__ rowptr,
    int2* __restrict__ csw, int N, int E)
{
    __shared__ int cur[512];
    int b = blockIdx.x;
    int tid = threadIdx.x;
    int node0 = b << 9;
    int nNodes = N - node0; if (nNodes > 512) nNodes = 512;
    for (int i = tid; i < nNodes; i += 256)
        cur[i] = rowptr[node0 + i];
    __syncthreads();
    int start = rowptr[node0];
    int end = (node0 + 512 >= N) ? E : rowptr[node0 + 512];
    for (int i = start + tid; i < end; i += 256) {
        int2 p = csw2[i];
        int dstLow = (int)(((unsigned)p.x) >> 17);
        int src = p.x & 0x1FFFF;
        int pos = atomicAdd(&cur[dstLow], 1);
        csw[pos] = make_int2(src, p.y);
    }
}

// ---------------------------------------------------------------------------
// x -> bf16 copy (gather payload for conv1)
// ---------------------------------------------------------------------------
__global__ __launch_bounds__(256) void xbf_kernel(
    const float* __restrict__ x, ushort* __restrict__ xbf, int total4)
{
    int i = blockIdx.x * 256 + threadIdx.x;
    if (i >= total4) return;
    float4 v = *(const float4*)(x + (size_t)i * 4);
    ushort4 h;
    h.x = f2bf(v.x); h.y = f2bf(v.y); h.z = f2bf(v.z); h.w = f2bf(v.w);
    *(ushort4*)(xbf + (size_t)i * 4) = h;
}

// ---------------------------------------------------------------------------
// Weight prep -> fragment-major split-bf16 layouts (coalesced B loads):
// W1f[kk:4][hl:2][kc:4][n:128][e:8]   (K=128: agg1|x)
// W2f[kk:8][hl:2][kc:4][n:128][e:8]   (K=256: agg2|h1)
// Wgf[kk:6][p:4 (sH,sL,tH,tL)][kc:4][n:128][e:8]  (K=192: h2|x)
// ---------------------------------------------------------------------------
__global__ __launch_bounds__(256) void prep_weights_kernel(
    const float* __restrict__ Wrel1, const float* __restrict__ Wroot1,
    const float* __restrict__ Wrel2, const float* __restrict__ Wroot2,
    const float* __restrict__ Wsig, const float* __restrict__ Wtanh,
    ushort* __restrict__ W1f, ushort* __restrict__ W2f, ushort* __restrict__ Wgf)
{
    int gid = blockIdx.x * 256 + threadIdx.x;
    if (gid < 32768) {
        int e = gid & 7, nn = (gid >> 3) & 127, kc = (gid >> 10) & 3;
        int hl = (gid >> 12) & 1, kk = gid >> 13;
        int k = kk * 32 + kc * 8 + e;
        float v = (k < 64) ? Wrel1[(size_t)k * 128 + nn]
                           : Wroot1[(size_t)(k - 64) * 128 + nn];
        ushort hi = f2bf(v);
        W1f[gid] = hl ? f2bf(v - bf2f(hi)) : hi;
        return;
    }
    int g2 = gid - 32768;
    if (g2 < 65536) {
        int e = g2 & 7, nn = (g2 >> 3) & 127, kc = (g2 >> 10) & 3;
        int hl = (g2 >> 12) & 1, kk = g2 >> 13;
        int k = kk * 32 + kc * 8 + e;
        float v = (k < 128) ? Wrel2[(size_t)k * 128 + nn]
                            : Wroot2[(size_t)(k - 128) * 128 + nn];
        ushort hi = f2bf(v);
        W2f[g2] = hl ? f2bf(v - bf2f(hi)) : hi;
        return;
    }
    int g3 = g2 - 65536;
    if (g3 < 98304) {
        int e = g3 & 7, nn = (g3 >> 3) & 127, kc = (g3 >> 10) & 3;
        int p = (g3 >> 12) & 3, kk = g3 >> 14;
        int k = kk * 32 + kc * 8 + e;
        float v = (p < 2) ? Wsig[(size_t)k * 128 + nn]
                          : Wtanh[(size_t)k * 128 + nn];
        ushort hi = f2bf(v);
        Wgf[g3] = (p & 1) ? f2bf(v - bf2f(hi)) : hi;
    }
}

// ---------------------------------------------------------------------------
// Fused conv1 (32-row tile, f32 LDS agg): h1bf = bf16(leaky([agg1|x]@W1 + b))
// ---------------------------------------------------------------------------
__global__ __launch_bounds__(256) void conv1_fused_kernel(
    const float* __restrict__ x, const ushort* __restrict__ xbf,
    const int* __restrict__ rowptr, const int2* __restrict__ csw,
    const ushort* __restrict__ W1f, const float* __restrict__ brel,
    ushort* __restrict__ h1bf, int n)
{
    __shared__ __align__(16) float agg[32 * 68];   // 8704 B

    int tid = threadIdx.x;
    int lane = tid & 63;
    int wv = tid >> 6;
    int mr = lane & 15;
    int kc = lane >> 4;          // 0..3
    int i0 = blockIdx.x * 32;

    // ---- gather phase: 16 lanes/node, 16 groups, 2 iters ----
    {
        int q = tid & 15;
        int g = tid >> 4;
#pragma unroll
        for (int it = 0; it < 2; ++it) {
            int rl = it * 16 + g;
            int node = i0 + rl;
            float ax = 0.f, ay = 0.f, az = 0.f, aw = 0.f;
            if (node < n) {
                int b = rowptr[node], e = rowptr[node + 1];
                for (int cb = b; cb < e; cb += 16) {
                    int cnt = e - cb; if (cnt > 16) cnt = 16;
                    int sIdx = 0; float sW = 0.f;
                    if (q < cnt) {
                        int2 p = csw[cb + q];
                        sIdx = p.x; sW = __int_as_float(p.y);
                    }
                    int j = 0;
                    for (; j + 8 <= cnt; j += 8) {
                        int si[8]; float wi[8]; ushort4 fv[8];
#pragma unroll
                        for (int u = 0; u < 8; ++u) {
                            si[u] = __shfl(sIdx, j + u, 16);
                            wi[u] = __shfl(sW, j + u, 16);
                        }
#pragma unroll
                        for (int u = 0; u < 8; ++u)
                            fv[u] = *(const ushort4*)(xbf + (size_t)si[u] * 64 + q * 4);
#pragma unroll
                        for (int u = 0; u < 8; ++u) {
                            ax += wi[u] * bf2f(fv[u].x);
                            ay += wi[u] * bf2f(fv[u].y);
                            az += wi[u] * bf2f(fv[u].z);
                            aw += wi[u] * bf2f(fv[u].w);
                        }
                    }
                    for (; j < cnt; ++j) {
                        int s0 = __shfl(sIdx, j, 16); float w0 = __shfl(sW, j, 16);
                        ushort4 f0 = *(const ushort4*)(xbf + (size_t)s0 * 64 + q * 4);
                        ax += w0 * bf2f(f0.x); ay += w0 * bf2f(f0.y);
                        az += w0 * bf2f(f0.z); aw += w0 * bf2f(f0.w);
                    }
                }
            }
            *(float4*)&agg[rl * 68 + q * 4] = make_float4(ax, ay, az, aw);
        }
    }
    __syncthreads();

    // ---- GEMM ----
    int t0 = wv * 2;
    const ushort* Wp = W1f + kc * 1024 + t0 * 128 + mr * 8;
    f32x4 acc[2][2] = {};

#pragma unroll
    for (int kk = 0; kk < 2; ++kk) {      // A from LDS agg (K 0..63), split on the fly
        short8 bH0 = *(const short8*)(Wp + kk * 8192);
        short8 bH1 = *(const short8*)(Wp + kk * 8192 + 128);
        short8 bL0 = *(const short8*)(Wp + kk * 8192 + 4096);
        short8 bL1 = *(const short8*)(Wp + kk * 8192 + 4096 + 128);
#pragma unroll
        for (int sub = 0; sub < 2; ++sub) {
            short8 aH, aL;
            split8(&agg[(sub * 16 + mr) * 68 + kk * 32 + kc * 8], aH, aL);
            MFMA(acc[sub][0], aH, bH0); MFMA(acc[sub][0], aH, bL0); MFMA(acc[sub][0], aL, bH0);
            MFMA(acc[sub][1], aH, bH1); MFMA(acc[sub][1], aH, bL1); MFMA(acc[sub][1], aL, bH1);
        }
    }
#pragma unroll
    for (int kk = 2; kk < 4; ++kk) {      // A from x (K 64..127), exact split
        short8 bH0 = *(const short8*)(Wp + kk * 8192);
        short8 bH1 = *(const short8*)(Wp + kk * 8192 + 128);
        short8 bL0 = *(const short8*)(Wp + kk * 8192 + 4096);
        short8 bL1 = *(const short8*)(Wp + kk * 8192 + 4096 + 128);
#pragma unroll
        for (int sub = 0; sub < 2; ++sub) {
            int row = i0 + sub * 16 + mr; if (row > n - 1) row = n - 1;
            short8 aH, aL;
            split8(x + (size_t)row * 64 + (kk - 2) * 32 + kc * 8, aH, aL);
            MFMA(acc[sub][0], aH, bH0); MFMA(acc[sub][0], aH, bL0); MFMA(acc[sub][0], aL, bH0);
            MFMA(acc[sub][1], aH, bH1); MFMA(acc[sub][1], aH, bL1); MFMA(acc[sub][1], aL, bH1);
        }
    }

#pragma unroll
    for (int tt = 0; tt < 2; ++tt) {
        int c = (t0 + tt) * 16 + mr;
        float bv = brel[c];
#pragma unroll
        for (int sub = 0; sub < 2; ++sub)
#pragma unroll
            for (int j = 0; j < 4; ++j) {
                int r = i0 + sub * 16 + kc * 4 + j;
                if (r < n)
                    h1bf[(size_t)r * 128 + c] = f2bf(LEAKY(acc[sub][tt][j] + bv));
            }
    }
}

// ---------------------------------------------------------------------------
// Fused conv2 + gate + pool (32-row tile, f32 LDS agg/h2, split on the fly)
// ---------------------------------------------------------------------------
__global__ __launch_bounds__(256) void conv2_gate_kernel(
    const ushort* __restrict__ h1bf, const float* __restrict__ x,
    const int* __restrict__ rowptr, const int2* __restrict__ csw,
    const ushort* __restrict__ W2f, const float* __restrict__ brel,
    const ushort* __restrict__ Wgf, const float* __restrict__ bsig,
    const float* __restrict__ btanh, const int* __restrict__ batch,
    float* __restrict__ pooled, int n)
{
    __shared__ __align__(16) float agg[32 * 132];   // 16896 B: agg2 -> h2 -> gs
    __shared__ int bS[32];
    float* gs = agg;                                 // alias (stride 128)

    int tid = threadIdx.x;
    int lane = tid & 63;
    int wv = tid >> 6;
    int mr = lane & 15;
    int kc = lane >> 4;
    int i0 = blockIdx.x * 32;

    // ---- gather phase: 32 lanes/node, 8 groups, 4 iters ----
    {
        int q = tid & 31;
        int g = tid >> 5;
#pragma unroll
        for (int it = 0; it < 4; ++it) {
            int rl = it * 8 + g;
            int node = i0 + rl;
            float ax = 0.f, ay = 0.f, az = 0.f, aw = 0.f;
            if (node < n) {
                int b = rowptr[node], e = rowptr[node + 1];
                for (int cb = b; cb < e; cb += 32) {
                    int cnt = e - cb; if (cnt > 32) cnt = 32;
                    int sIdx = 0; float sW = 0.f;
                    if (q < cnt) {
                        int2 p = csw[cb + q];
                        sIdx = p.x; sW = __int_as_float(p.y);
                    }
                    int j = 0;
                    for (; j + 8 <= cnt; j += 8) {
                        int si[8]; float wi[8]; ushort4 fv[8];
#pragma unroll
                        for (int u = 0; u < 8; ++u) {
                            si[u] = __shfl(sIdx, j + u, 32);
                            wi[u] = __shfl(sW, j + u, 32);
                        }
#pragma unroll
                        for (int u = 0; u < 8; ++u)
                            fv[u] = *(const ushort4*)(h1bf + (size_t)si[u] * 128 + q * 4);
#pragma unroll
                        for (int u = 0; u < 8; ++u) {
                            ax += wi[u] * bf2f(fv[u].x);
                            ay += wi[u] * bf2f(fv[u].y);
                            az += wi[u] * bf2f(fv[u].z);
                            aw += wi[u] * bf2f(fv[u].w);
                        }
                    }
                    for (; j < cnt; ++j) {
                        int s0 = __shfl(sIdx, j, 32); float w0 = __shfl(sW, j, 32);
                        ushort4 f0 = *(const ushort4*)(h1bf + (size_t)s0 * 128 + q * 4);
                        ax += w0 * bf2f(f0.x); ay += w0 * bf2f(f0.y);
                        az += w0 * bf2f(f0.z); aw += w0 * bf2f(f0.w);
                    }
                }
            }
            *(float4*)&agg[rl * 132 + q * 4] = make_float4(ax, ay, az, aw);
        }
    }
    if (tid < 32) {
        int r = i0 + tid;
        bS[tid] = (r < n) ? batch[r] : -1;
    }
    __syncthreads();

    int t0 = wv * 2;

    // ---- GEMM1: h2 = leaky([agg2|h1] @ W2 + brel) ----
    f32x4 acc[2][2] = {};
    {
        const ushort* Wp = W2f + kc * 1024 + t0 * 128 + mr * 8;
#pragma unroll
        for (int kk = 0; kk < 4; ++kk) {           // A = LDS agg f32 (K 0..127)
            short8 bH0 = *(const short8*)(Wp + kk * 8192);
            short8 bH1 = *(const short8*)(Wp + kk * 8192 + 128);
            short8 bL0 = *(const short8*)(Wp + kk * 8192 + 4096);
            short8 bL1 = *(const short8*)(Wp + kk * 8192 + 4096 + 128);
#pragma unroll
            for (int sub = 0; sub < 2; ++sub) {
                short8 aH, aL;
                split8(&agg[(sub * 16 + mr) * 132 + kk * 32 + kc * 8], aH, aL);
                MFMA(acc[sub][0], aH, bH0); MFMA(acc[sub][0], aH, bL0); MFMA(acc[sub][0], aL, bH0);
                MFMA(acc[sub][1], aH, bH1); MFMA(acc[sub][1], aH, bL1); MFMA(acc[sub][1], aL, bH1);
            }
        }
#pragma unroll
        for (int kk = 4; kk < 8; ++kk) {           // A = h1bf global (K 128..255)
            short8 bH0 = *(const short8*)(Wp + kk * 8192);
            short8 bH1 = *(const short8*)(Wp + kk * 8192 + 128);
            short8 bL0 = *(const short8*)(Wp + kk * 8192 + 4096);
            short8 bL1 = *(const short8*)(Wp + kk * 8192 + 4096 + 128);
#pragma unroll
            for (int sub = 0; sub < 2; ++sub) {
                int row = i0 + sub * 16 + mr; if (row > n - 1) row = n - 1;
                short8 aH = *(const short8*)(h1bf + (size_t)row * 128 + (kk - 4) * 32 + kc * 8);
                MFMA(acc[sub][0], aH, bH0); MFMA(acc[sub][0], aH, bL0);
                MFMA(acc[sub][1], aH, bH1); MFMA(acc[sub][1], aH, bL1);
            }
        }
    }
    __syncthreads();   // all agg reads complete -> safe to overwrite with h2

#pragma unroll
    for (int tt = 0; tt < 2; ++tt) {
        int c = (t0 + tt) * 16 + mr;
        float bv = brel[c];
#pragma unroll
        for (int sub = 0; sub < 2; ++sub)
#pragma unroll
            for (int j = 0; j < 4; ++j) {
                int rl = sub * 16 + kc * 4 + j;
                agg[rl * 132 + c] = LEAKY(acc[sub][tt][j] + bv);
            }
    }
    __syncthreads();

    // ---- GEMM2: gate over [h2|x] ----
    f32x4 as[2][2] = {}, at_[2][2] = {};
    {
        const ushort* Wp = Wgf + kc * 1024 + t0 * 128 + mr * 8;
#pragma unroll
        for (int kk = 0; kk < 4; ++kk) {           // A = LDS h2 f32 (K 0..127)
            short8 sH0 = *(const short8*)(Wp + kk * 16384);
            short8 sH1 = *(const short8*)(Wp + kk * 16384 + 128);
            short8 sL0 = *(const short8*)(Wp + kk * 16384 + 4096);
            short8 sL1 = *(const short8*)(Wp + kk * 16384 + 4096 + 128);
            short8 tH0 = *(const short8*)(Wp + kk * 16384 + 8192);
            short8 tH1 = *(const short8*)(Wp + kk * 16384 + 8192 + 128);
            short8 tL0 = *(const short8*)(Wp + kk * 16384 + 12288);
            short8 tL1 = *(const short8*)(Wp + kk * 16384 + 12288 + 128);
#pragma unroll
            for (int sub = 0; sub < 2; ++sub) {
                short8 aH, aL;
                split8(&agg[(sub * 16 + mr) * 132 + kk * 32 + kc * 8], aH, aL);
                MFMA(as[sub][0], aH, sH0); MFMA(as[sub][0], aH, sL0); MFMA(as[sub][0], aL, sH0);
                MFMA(as[sub][1], aH, sH1); MFMA(as[sub][1], aH, sL1); MFMA(as[sub][1], aL, sH1);
                MFMA(at_[sub][0], aH, tH0); MFMA(at_[sub][0], aH, tL0); MFMA(at_[sub][0], aL, tH0);
                MFMA(at_[sub][1], aH, tH1); MFMA(at_[sub][1], aH, tL1); MFMA(at_[sub][1], aL, tH1);
            }
        }
#pragma unroll
        for (int kk = 4; kk < 6; ++kk) {           // A = x (K 128..191), exact split
            short8 sH0 = *(const short8*)(Wp + kk * 16384);
            short8 sH1 = *(const short8*)(Wp + kk * 16384 + 128);
            short8 sL0 = *(const short8*)(Wp + kk * 16384 + 4096);
            short8 sL1 = *(const short8*)(Wp + kk * 16384 + 4096 + 128);
            short8 tH0 = *(const short8*)(Wp + kk * 16384 + 8192);
            short8 tH1 = *(const short8*)(Wp + kk * 16384 + 8192 + 128);
            short8 tL0 = *(const short8*)(Wp + kk * 16384 + 12288);
            short8 tL1 = *(const short8*)(Wp + kk * 16384 + 12288 + 128);
#pragma unroll
            for (int sub = 0; sub < 2; ++sub) {
                int row = i0 + sub * 16 + mr; if (row > n - 1) row = n - 1;
                short8 aH, aL;
                split8(x + (size_t)row * 64 + (kk - 4) * 32 + kc * 8, aH, aL);
                MFMA(as[sub][0], aH, sH0); MFMA(as[sub][0], aH, sL0); MFMA(as[sub][0], aL, sH0);
                MFMA(as[sub][1], aH, sH1); MFMA(as[sub][1], aH, sL1); MFMA(as[sub][1], aL, sH1);
                MFMA(at_[sub][0], aH, tH0); MFMA(at_[sub][0], aH, tL0); MFMA(at_[sub][0], aL, tH0);
                MFMA(at_[sub][1], aH, tH1); MFMA(at_[sub][1], aH, tL1); MFMA(at_[sub][1], aL, tH1);
            }
        }
    }
    __syncthreads();   // h2 LDS reads complete -> safe to alias gs

    // ---- gate epilogue ----
#pragma unroll
    for (int tt = 0; tt < 2; ++tt) {
        int c = (t0 + tt) * 16 + mr;
        float bsv = bsig[c], btv = btanh[c];
#pragma unroll
        for (int sub = 0; sub < 2; ++sub)
#pragma unroll
            for (int j = 0; j < 4; ++j) {
                int rl = sub * 16 + kc * 4 + j;
                float s = as[sub][tt][j] + bsv;
                s = fminf(fmaxf(s, -30.f), 30.f);
                float ta = at_[sub][tt][j] + btv;
                ta = fminf(fmaxf(ta, -15.f), 15.f);
                float e2 = __expf(2.f * ta);
                float th = (e2 - 1.f) / (e2 + 1.f);
                gs[rl * 128 + c] = th / (1.f + __expf(s));
            }
    }
    __syncthreads();

    // ---- run-compressed pooling ----
    int j = tid & 127;
    int m0 = (tid >> 7) * 16;
    float acc2 = 0.f;
    int cur = -1;
    for (int m = m0; m < m0 + 16; ++m) {
        int b = bS[m];
        if (b < 0) break;
        if (b != cur) {
            if (cur >= 0) atomicAdd(&pooled[(size_t)cur * 128 + j], acc2);
            cur = b;
            acc2 = 0.f;
        }
        acc2 += gs[m * 128 + j];
    }
    if (cur >= 0) atomicAdd(&pooled[(size_t)cur * 128 + j], acc2);
}

// ---------------------------------------------------------------------------
// Final per-graph MLP
// ---------------------------------------------------------------------------
__global__ __launch_bounds__(256) void mlp_kernel(
    const float* __restrict__ pooled,
    const float* __restrict__ Wf1, const float* __restrict__ bf1,
    const float* __restrict__ Wf2, const float* __restrict__ bf2,
    const float* __restrict__ Wout, const float* __restrict__ bout,
    float* __restrict__ out)
{
    __shared__ float p[128];
    __shared__ float f1[128];
    __shared__ float f2[258];
    __shared__ float red[4];

    int g = blockIdx.x;
    int tid = threadIdx.x;

    if (tid < 128) p[tid] = pooled[(size_t)g * 128 + tid];
    __syncthreads();

    if (tid < 128) {
        float a = bf1[tid];
        for (int k = 0; k < 128; ++k) a += p[k] * Wf1[k * 128 + tid];
        f1[tid] = LEAKY(a);
    }
    __syncthreads();

    for (int j = tid; j < 258; j += 256) {
        float a = bf2[j];
        for (int k = 0; k < 128; ++k) a += f1[k] * Wf2[k * 258 + j];
        f2[j] = LEAKY(a);
    }
    __syncthreads();

    float a = 0.f;
    for (int j = tid; j < 258; j += 256) a += f2[j] * Wout[j];
#pragma unroll
    for (int off = 32; off > 0; off >>= 1) a += __shfl_down(a, off, 64);
    if ((tid & 63) == 0) red[tid >> 6] = a;
    __syncthreads();
    if (tid == 0) {
        float v = red[0] + red[1] + red[2] + red[3] + bout[0];
        out[g] = 1.f / (1.f + expf(-v));
    }
}

// ---------------------------------------------------------------------------
extern "C" void kernel_launch(void* const* d_in, const int* in_sizes, int n_in,
                              void* d_out, int out_size, void* d_ws, size_t ws_size,
                              hipStream_t stream)
{
    const float* x     = (const float*)d_in[0];
    const int*   ei    = (const int*)d_in[1];
    const int*   batch = (const int*)d_in[2];
    const float* ea    = (const float*)d_in[3];
    const float* Wrel1 = (const float*)d_in[4];
    const float* brel1 = (const float*)d_in[5];
    const float* Wroot1= (const float*)d_in[6];
    const float* Wrel2 = (const float*)d_in[7];
    const float* brel2 = (const float*)d_in[8];
    const float* Wroot2= (const float*)d_in[9];
    const float* Wsig  = (const float*)d_in[10];
    const float* bsig  = (const float*)d_in[11];
    const float* Wtanh = (const float*)d_in[12];
    const float* btanh = (const float*)d_in[13];
    const float* Wf1   = (const float*)d_in[14];
    const float* bf1   = (const float*)d_in[15];
    const float* Wf2   = (const float*)d_in[16];
    const float* bf2   = (const float*)d_in[17];
    const float* Wout  = (const float*)d_in[18];
    const float* bout  = (const float*)d_in[19];

    int N = in_sizes[2];
    int E = in_sizes[3];
    int NB = (N + 511) / 512;      // buckets of 512 nodes (N <= 131072)

    char* base = (char*)d_ws;
    size_t off = 0;
    auto alloc = [&](size_t bytes) {
        char* p = base + off;
        off += (bytes + 255) & ~(size_t)255;
        return p;
    };
    ushort*   h1bf  = (ushort*)alloc((size_t)N * 128 * 2);
    ushort*   xbf   = (ushort*)alloc((size_t)N * 64 * 2);
    int*      rowptr= (int*)alloc((size_t)(N + 1) * 4);
    int*      cursor= (int*)alloc((size_t)N * 4);
    int*      bsum  = (int*)alloc(512 * 4);
    int*      bcur  = (int*)alloc(256 * 4);
    int2*     csw   = (int2*)alloc((size_t)E * 8);
    int2*     csw2  = (int2*)alloc((size_t)E * 8);
    ushort*   W1f   = (ushort*)alloc(32768 * 2);
    ushort*   W2f   = (ushort*)alloc(65536 * 2);
    ushort*   Wgf   = (ushort*)alloc(98304 * 2);
    float*    pooled= (float*)alloc(256 * 128 * 4);

    int eblk = (E + 255) / 256;
    int nblk1 = (N + 1023) / 1024;
    int cblk = (N + 31) / 32;
    int ablk = (E + CHUNK - 1) / CHUNK;

    hipMemsetAsync(cursor, 0, (size_t)N * sizeof(int), stream);
    hipMemsetAsync(bcur, 0, 256 * sizeof(int), stream);
    hipMemsetAsync(pooled, 0, (size_t)256 * 128 * sizeof(float), stream);

    prep_weights_kernel<<<768, 256, 0, stream>>>(Wrel1, Wroot1, Wrel2, Wroot2,
                                                 Wsig, Wtanh, W1f, W2f, Wgf);
    xbf_kernel<<<(N * 16 + 255) / 256, 256, 0, stream>>>(x, xbf, N * 16);

    // ---- CSR build ----
    hist_kernel<<<eblk, 256, 0, stream>>>(ei, cursor, E);
    scan1_kernel<<<nblk1, 256, 0, stream>>>(cursor, rowptr, bsum, N);
    scan2_kernel<<<1, 512, 0, stream>>>(bsum, nblk1);
    scan3_kernel<<<(N + 255) / 256, 256, 0, stream>>>(rowptr, bsum, N, E);
    partA_kernel<<<ablk, 256, 0, stream>>>(ei, ea, rowptr, bcur, csw2, E, NB);
    partB_kernel<<<NB, 256, 0, stream>>>(csw2, rowptr, csw, N, E);

    // ---- fused conv1 (gather + GEMM) ----
    conv1_fused_kernel<<<cblk, 256, 0, stream>>>(x, xbf, rowptr, csw,
                                                 W1f, brel1, h1bf, N);

    // ---- fused conv2 + gate + pool (gather + 2 GEMMs) ----
    conv2_gate_kernel<<<cblk, 256, 0, stream>>>(h1bf, x, rowptr, csw,
                                                W2f, brel2, Wgf, bsig, btanh,
                                                batch, pooled, N);

    // ---- final MLP ----
    mlp_kernel<<<256, 256, 0, stream>>>(pooled, Wf1, bf1, Wf2, bf2, Wout, bout,
                                        (float*)d_out);
}

// Round 14
// 302.808 us; speedup vs baseline: 1.4508x; 1.1753x over previous
//
#include <hip/hip_runtime.h>
#include <cstdint>

#define RELU_COEF 0.05f
#define LEAKY(v) ((v) > 0.f ? (v) : RELU_COEF * (v))

typedef __attribute__((ext_vector_type(8))) short short8;
typedef __attribute__((ext_vector_type(4))) float f32x4;

#define MFMA(acc, a, b) \
    acc = __builtin_amdgcn_mfma_f32_16x16x32_bf16(a, b, acc, 0, 0, 0)

__device__ inline ushort f2bf(float f) {
    union { float f; uint32_t u; } v; v.f = f;
    return (ushort)((v.u + 0x7FFFu + ((v.u >> 16) & 1u)) >> 16);
}
__device__ inline float bf2f(ushort h) {
    union { uint32_t u; float f; } v; v.u = ((uint32_t)h) << 16;
    return v.f;
}
__device__ inline void split8(const float* p, short8& h8, short8& l8) {
    float4 a = *(const float4*)p;
    float4 b = *(const float4*)(p + 4);
    float v[8] = {a.x, a.y, a.z, a.w, b.x, b.y, b.z, b.w};
    short8 hh, ll;
#pragma unroll
    for (int i = 0; i < 8; ++i) {
        ushort hi = f2bf(v[i]);
        hh[i] = (short)hi;
        ll[i] = (short)f2bf(v[i] - bf2f(hi));
    }
    h8 = hh; l8 = ll;
}

// ---------------------------------------------------------------------------
// CSR build v2 (no global node-hist/scan):
//   bhist (chunk-local bucket hist) -> bscan (bucket offsets) ->
//   partA (bucket partition)        -> partB (per-bucket degree hist + scan:
//                                      writes rowptr AND exact-sorted csw)
// Assumes N <= 131072 (src fits 17 bits, bucket = dst>>9 fits 8 bits).
// ---------------------------------------------------------------------------
#define CHUNK 4096

__global__ __launch_bounds__(256) void bhist_kernel(
    const int* __restrict__ ei, int* __restrict__ bhist, int E)
{
    __shared__ int cnt[256];
    int tid = threadIdx.x;
    cnt[tid] = 0;
    __syncthreads();
    long long base = (long long)blockIdx.x * CHUNK;
    int cntHere = (int)((E - base) < CHUNK ? (E - base) : CHUNK);
    for (int i = tid; i < cntHere; i += 256)
        atomicAdd(&cnt[ei[(size_t)E + base + i] >> 9], 1);
    __syncthreads();
    if (cnt[tid] > 0) atomicAdd(&bhist[tid], cnt[tid]);
}

__global__ __launch_bounds__(256) void bscan_kernel(
    const int* __restrict__ bhist, int* __restrict__ bptr, int E)
{
    __shared__ int ts[256];
    int tid = threadIdx.x;
    int v = bhist[tid];
    ts[tid] = v;
    __syncthreads();
    for (int off = 1; off < 256; off <<= 1) {
        int t = (tid >= off) ? ts[tid - off] : 0;
        __syncthreads();
        ts[tid] += t;
        __syncthreads();
    }
    bptr[tid] = ts[tid] - v;      // exclusive prefix
    if (tid == 255) bptr[256] = E;
}

// partA: partition edges into 512-node buckets with run-coalesced writes.
__global__ __launch_bounds__(256) void partA_kernel(
    const int* __restrict__ ei, const float* __restrict__ ea,
    const int* __restrict__ bptr, int* __restrict__ bucketCursor,
    int2* __restrict__ csw2, int E, int NB)
{
    __shared__ int cnt[256];
    __shared__ int scanx[256];
    __shared__ int runc[256];
    __shared__ int gbase[256];
    __shared__ int2 staged[CHUNK];
    __shared__ unsigned char bkt[CHUNK];

    int tid = threadIdx.x;
    long long base = (long long)blockIdx.x * CHUNK;
    int cntHere = (int)((E - base) < CHUNK ? (E - base) : CHUNK);

    cnt[tid] = 0; runc[tid] = 0;
    __syncthreads();

    // phase 1: histogram
    for (int i = tid; i < cntHere; i += 256) {
        int d = ei[(size_t)E + base + i];
        atomicAdd(&cnt[d >> 9], 1);
    }
    __syncthreads();

    // exclusive scan over 256 buckets
    int v = cnt[tid];
    scanx[tid] = v;
    __syncthreads();
    for (int off = 1; off < 256; off <<= 1) {
        int t = (tid >= off) ? scanx[tid - off] : 0;
        __syncthreads();
        scanx[tid] += t;
        __syncthreads();
    }
    int excl = scanx[tid] - v;
    if (tid < NB && v > 0)
        gbase[tid] = bptr[tid] + atomicAdd(&bucketCursor[tid], v);
    scanx[tid] = excl;
    __syncthreads();

    // phase 2: scatter into LDS, bucket-ordered
    for (int i = tid; i < cntHere; i += 256) {
        long long e = base + i;
        int d = ei[(size_t)E + e];
        int b = d >> 9;
        int idx = scanx[b] + atomicAdd(&runc[b], 1);
        staged[idx] = make_int2(((d & 511) << 17) | ei[e], __float_as_int(ea[e]));
        bkt[idx] = (unsigned char)b;
    }
    __syncthreads();

    // phase 3: run-contiguous write-out
    for (int i = tid; i < cntHere; i += 256) {
        int b = bkt[i];
        csw2[gbase[b] + (i - scanx[b])] = staged[i];
    }
}

// partB: per-bucket degree histogram + scan (writes rowptr), then exact
// within-bucket CSR sort. All stores to one bucket window from one CU.
__global__ __launch_bounds__(256) void partB_kernel(
    const int2* __restrict__ csw2, const int* __restrict__ bptr,
    int* __restrict__ rowptr, int2* __restrict__ csw, int N, int E)
{
    __shared__ int hist[512];
    __shared__ int cur[512];
    __shared__ int ts[256];

    int b = blockIdx.x;
    int tid = threadIdx.x;
    int node0 = b << 9;
    int start = bptr[b], end = bptr[b + 1];

    hist[tid] = 0; hist[tid + 256] = 0;
    __syncthreads();
    for (int i = start + tid; i < end; i += 256) {
        int2 p = csw2[i];
        atomicAdd(&hist[((unsigned)p.x) >> 17], 1);
    }
    __syncthreads();

    // 512-entry exclusive scan (2 elems/thread)
    int v0 = hist[2 * tid], v1 = hist[2 * tid + 1];
    int s = v0 + v1;
    ts[tid] = s;
    __syncthreads();
    for (int off = 1; off < 256; off <<= 1) {
        int t = (tid >= off) ? ts[tid - off] : 0;
        __syncthreads();
        ts[tid] += t;
        __syncthreads();
    }
    int excl = ts[tid] - s;
    cur[2 * tid]     = start + excl;
    cur[2 * tid + 1] = start + excl + v0;
    __syncthreads();

    // write rowptr for this bucket's nodes
    int nNodes = N - node0; if (nNodes > 512) nNodes = 512;
    for (int i = tid; i < nNodes; i += 256)
        rowptr[node0 + i] = cur[i];
    if (b == (int)gridDim.x - 1 && tid == 0) rowptr[N] = E;
    __syncthreads();

    // exact sort into csw
    for (int i = start + tid; i < end; i += 256) {
        int2 p = csw2[i];
        int dstLow = (int)(((unsigned)p.x) >> 17);
        int src = p.x & 0x1FFFF;
        int pos = atomicAdd(&cur[dstLow], 1);
        csw[pos] = make_int2(src, p.y);
    }
}

// ---------------------------------------------------------------------------
// x -> bf16 copy (gather payload for conv1)
// ---------------------------------------------------------------------------
__global__ __launch_bounds__(256) void xbf_kernel(
    const float* __restrict__ x, ushort* __restrict__ xbf, int total4)
{
    int i = blockIdx.x * 256 + threadIdx.x;
    if (i >= total4) return;
    float4 v = *(const float4*)(x + (size_t)i * 4);
    ushort4 h;
    h.x = f2bf(v.x); h.y = f2bf(v.y); h.z = f2bf(v.z); h.w = f2bf(v.w);
    *(ushort4*)(xbf + (size_t)i * 4) = h;
}

// ---------------------------------------------------------------------------
// Weight prep -> fragment-major split-bf16 layouts (coalesced B loads)
// ---------------------------------------------------------------------------
__global__ __launch_bounds__(256) void prep_weights_kernel(
    const float* __restrict__ Wrel1, const float* __restrict__ Wroot1,
    const float* __restrict__ Wrel2, const float* __restrict__ Wroot2,
    const float* __restrict__ Wsig, const float* __restrict__ Wtanh,
    ushort* __restrict__ W1f, ushort* __restrict__ W2f, ushort* __restrict__ Wgf)
{
    int gid = blockIdx.x * 256 + threadIdx.x;
    if (gid < 32768) {
        int e = gid & 7, nn = (gid >> 3) & 127, kc = (gid >> 10) & 3;
        int hl = (gid >> 12) & 1, kk = gid >> 13;
        int k = kk * 32 + kc * 8 + e;
        float v = (k < 64) ? Wrel1[(size_t)k * 128 + nn]
                           : Wroot1[(size_t)(k - 64) * 128 + nn];
        ushort hi = f2bf(v);
        W1f[gid] = hl ? f2bf(v - bf2f(hi)) : hi;
        return;
    }
    int g2 = gid - 32768;
    if (g2 < 65536) {
        int e = g2 & 7, nn = (g2 >> 3) & 127, kc = (g2 >> 10) & 3;
        int hl = (g2 >> 12) & 1, kk = g2 >> 13;
        int k = kk * 32 + kc * 8 + e;
        float v = (k < 128) ? Wrel2[(size_t)k * 128 + nn]
                            : Wroot2[(size_t)(k - 128) * 128 + nn];
        ushort hi = f2bf(v);
        W2f[g2] = hl ? f2bf(v - bf2f(hi)) : hi;
        return;
    }
    int g3 = g2 - 65536;
    if (g3 < 98304) {
        int e = g3 & 7, nn = (g3 >> 3) & 127, kc = (g3 >> 10) & 3;
        int p = (g3 >> 12) & 3, kk = g3 >> 14;
        int k = kk * 32 + kc * 8 + e;
        float v = (p < 2) ? Wsig[(size_t)k * 128 + nn]
                          : Wtanh[(size_t)k * 128 + nn];
        ushort hi = f2bf(v);
        Wgf[g3] = (p & 1) ? f2bf(v - bf2f(hi)) : hi;
    }
}

// ---------------------------------------------------------------------------
// Fused conv1 (32-row tile, f32 LDS agg, prefetched edge chunks)
// ---------------------------------------------------------------------------
__global__ __launch_bounds__(256) void conv1_fused_kernel(
    const float* __restrict__ x, const ushort* __restrict__ xbf,
    const int* __restrict__ rowptr, const int2* __restrict__ csw,
    const ushort* __restrict__ W1f, const float* __restrict__ brel,
    ushort* __restrict__ h1bf, int n)
{
    __shared__ __align__(16) float agg[32 * 68];   // 8704 B

    int tid = threadIdx.x;
    int lane = tid & 63;
    int wv = tid >> 6;
    int mr = lane & 15;
    int kc = lane >> 4;
    int i0 = blockIdx.x * 32;

    // ---- gather phase: 16 lanes/node, prefetched 16-edge chunks ----
    {
        int q = tid & 15;
        int g = tid >> 4;
#pragma unroll
        for (int it = 0; it < 2; ++it) {
            int rl = it * 16 + g;
            int node = i0 + rl;
            float ax = 0.f, ay = 0.f, az = 0.f, aw = 0.f;
            if (node < n) {
                int b = rowptr[node], e = rowptr[node + 1];
                int cb = b;
                int cnt = e - cb; if (cnt > 16) cnt = 16;
                int2 pc = make_int2(0, 0);
                if (cnt > 0 && q < cnt) pc = csw[cb + q];
                while (cb < e) {
                    int nb2 = cb + 16;
                    int ncnt = e - nb2; if (ncnt > 16) ncnt = 16;
                    int2 np = make_int2(0, 0);
                    if (ncnt > 0 && q < ncnt) np = csw[nb2 + q];   // prefetch
                    int sIdx = pc.x; float sW = __int_as_float(pc.y);
                    int j = 0;
                    for (; j + 8 <= cnt; j += 8) {
                        int si[8]; float wi[8]; ushort4 fv[8];
#pragma unroll
                        for (int u = 0; u < 8; ++u) {
                            si[u] = __shfl(sIdx, j + u, 16);
                            wi[u] = __shfl(sW, j + u, 16);
                        }
#pragma unroll
                        for (int u = 0; u < 8; ++u)
                            fv[u] = *(const ushort4*)(xbf + (size_t)si[u] * 64 + q * 4);
#pragma unroll
                        for (int u = 0; u < 8; ++u) {
                            ax += wi[u] * bf2f(fv[u].x);
                            ay += wi[u] * bf2f(fv[u].y);
                            az += wi[u] * bf2f(fv[u].z);
                            aw += wi[u] * bf2f(fv[u].w);
                        }
                    }
                    for (; j < cnt; ++j) {
                        int s0 = __shfl(sIdx, j, 16); float w0 = __shfl(sW, j, 16);
                        ushort4 f0 = *(const ushort4*)(xbf + (size_t)s0 * 64 + q * 4);
                        ax += w0 * bf2f(f0.x); ay += w0 * bf2f(f0.y);
                        az += w0 * bf2f(f0.z); aw += w0 * bf2f(f0.w);
                    }
                    cb = nb2; cnt = ncnt; pc = np;
                }
            }
            *(float4*)&agg[rl * 68 + q * 4] = make_float4(ax, ay, az, aw);
        }
    }
    __syncthreads();

    // ---- GEMM ----
    int t0 = wv * 2;
    const ushort* Wp = W1f + kc * 1024 + t0 * 128 + mr * 8;
    f32x4 acc[2][2] = {};

#pragma unroll
    for (int kk = 0; kk < 2; ++kk) {      // A from LDS agg (K 0..63)
        short8 bH0 = *(const short8*)(Wp + kk * 8192);
        short8 bH1 = *(const short8*)(Wp + kk * 8192 + 128);
        short8 bL0 = *(const short8*)(Wp + kk * 8192 + 4096);
        short8 bL1 = *(const short8*)(Wp + kk * 8192 + 4096 + 128);
#pragma unroll
        for (int sub = 0; sub < 2; ++sub) {
            short8 aH, aL;
            split8(&agg[(sub * 16 + mr) * 68 + kk * 32 + kc * 8], aH, aL);
            MFMA(acc[sub][0], aH, bH0); MFMA(acc[sub][0], aH, bL0); MFMA(acc[sub][0], aL, bH0);
            MFMA(acc[sub][1], aH, bH1); MFMA(acc[sub][1], aH, bL1); MFMA(acc[sub][1], aL, bH1);
        }
    }
#pragma unroll
    for (int kk = 2; kk < 4; ++kk) {      // A from x (K 64..127), exact split
        short8 bH0 = *(const short8*)(Wp + kk * 8192);
        short8 bH1 = *(const short8*)(Wp + kk * 8192 + 128);
        short8 bL0 = *(const short8*)(Wp + kk * 8192 + 4096);
        short8 bL1 = *(const short8*)(Wp + kk * 8192 + 4096 + 128);
#pragma unroll
        for (int sub = 0; sub < 2; ++sub) {
            int row = i0 + sub * 16 + mr; if (row > n - 1) row = n - 1;
            short8 aH, aL;
            split8(x + (size_t)row * 64 + (kk - 2) * 32 + kc * 8, aH, aL);
            MFMA(acc[sub][0], aH, bH0); MFMA(acc[sub][0], aH, bL0); MFMA(acc[sub][0], aL, bH0);
            MFMA(acc[sub][1], aH, bH1); MFMA(acc[sub][1], aH, bL1); MFMA(acc[sub][1], aL, bH1);
        }
    }

#pragma unroll
    for (int tt = 0; tt < 2; ++tt) {
        int c = (t0 + tt) * 16 + mr;
        float bv = brel[c];
#pragma unroll
        for (int sub = 0; sub < 2; ++sub)
#pragma unroll
            for (int j = 0; j < 4; ++j) {
                int r = i0 + sub * 16 + kc * 4 + j;
                if (r < n)
                    h1bf[(size_t)r * 128 + c] = f2bf(LEAKY(acc[sub][tt][j] + bv));
            }
    }
}

// ---------------------------------------------------------------------------
// Fused conv2 + gate + pool (32-row tile, prefetched edge chunks)
// ---------------------------------------------------------------------------
__global__ __launch_bounds__(256) void conv2_gate_kernel(
    const ushort* __restrict__ h1bf, const float* __restrict__ x,
    const int* __restrict__ rowptr, const int2* __restrict__ csw,
    const ushort* __restrict__ W2f, const float* __restrict__ brel,
    const ushort* __restrict__ Wgf, const float* __restrict__ bsig,
    const float* __restrict__ btanh, const int* __restrict__ batch,
    float* __restrict__ pooled, int n)
{
    __shared__ __align__(16) float agg[32 * 132];   // agg2 -> h2 -> gs
    __shared__ int bS[32];
    float* gs = agg;

    int tid = threadIdx.x;
    int lane = tid & 63;
    int wv = tid >> 6;
    int mr = lane & 15;
    int kc = lane >> 4;
    int i0 = blockIdx.x * 32;

    // ---- gather phase: 32 lanes/node, prefetched 32-edge chunks ----
    {
        int q = tid & 31;
        int g = tid >> 5;
#pragma unroll
        for (int it = 0; it < 4; ++it) {
            int rl = it * 8 + g;
            int node = i0 + rl;
            float ax = 0.f, ay = 0.f, az = 0.f, aw = 0.f;
            if (node < n) {
                int b = rowptr[node], e = rowptr[node + 1];
                int cb = b;
                int cnt = e - cb; if (cnt > 32) cnt = 32;
                int2 pc = make_int2(0, 0);
                if (cnt > 0 && q < cnt) pc = csw[cb + q];
                while (cb < e) {
                    int nb2 = cb + 32;
                    int ncnt = e - nb2; if (ncnt > 32) ncnt = 32;
                    int2 np = make_int2(0, 0);
                    if (ncnt > 0 && q < ncnt) np = csw[nb2 + q];   // prefetch
                    int sIdx = pc.x; float sW = __int_as_float(pc.y);
                    int j = 0;
                    for (; j + 8 <= cnt; j += 8) {
                        int si[8]; float wi[8]; ushort4 fv[8];
#pragma unroll
                        for (int u = 0; u < 8; ++u) {
                            si[u] = __shfl(sIdx, j + u, 32);
                            wi[u] = __shfl(sW, j + u, 32);
                        }
#pragma unroll
                        for (int u = 0; u < 8; ++u)
                            fv[u] = *(const ushort4*)(h1bf + (size_t)si[u] * 128 + q * 4);
#pragma unroll
                        for (int u = 0; u < 8; ++u) {
                            ax += wi[u] * bf2f(fv[u].x);
                            ay += wi[u] * bf2f(fv[u].y);
                            az += wi[u] * bf2f(fv[u].z);
                            aw += wi[u] * bf2f(fv[u].w);
                        }
                    }
                    for (; j < cnt; ++j) {
                        int s0 = __shfl(sIdx, j, 32); float w0 = __shfl(sW, j, 32);
                        ushort4 f0 = *(const ushort4*)(h1bf + (size_t)s0 * 128 + q * 4);
                        ax += w0 * bf2f(f0.x); ay += w0 * bf2f(f0.y);
                        az += w0 * bf2f(f0.z); aw += w0 * bf2f(f0.w);
                    }
                    cb = nb2; cnt = ncnt; pc = np;
                }
            }
            *(float4*)&agg[rl * 132 + q * 4] = make_float4(ax, ay, az, aw);
        }
    }
    if (tid < 32) {
        int r = i0 + tid;
        bS[tid] = (r < n) ? batch[r] : -1;
    }
    __syncthreads();

    int t0 = wv * 2;

    // ---- GEMM1: h2 = leaky([agg2|h1] @ W2 + brel) ----
    f32x4 acc[2][2] = {};
    {
        const ushort* Wp = W2f + kc * 1024 + t0 * 128 + mr * 8;
#pragma unroll
        for (int kk = 0; kk < 4; ++kk) {           // A = LDS agg f32 (K 0..127)
            short8 bH0 = *(const short8*)(Wp + kk * 8192);
            short8 bH1 = *(const short8*)(Wp + kk * 8192 + 128);
            short8 bL0 = *(const short8*)(Wp + kk * 8192 + 4096);
            short8 bL1 = *(const short8*)(Wp + kk * 8192 + 4096 + 128);
#pragma unroll
            for (int sub = 0; sub < 2; ++sub) {
                short8 aH, aL;
                split8(&agg[(sub * 16 + mr) * 132 + kk * 32 + kc * 8], aH, aL);
                MFMA(acc[sub][0], aH, bH0); MFMA(acc[sub][0], aH, bL0); MFMA(acc[sub][0], aL, bH0);
                MFMA(acc[sub][1], aH, bH1); MFMA(acc[sub][1], aH, bL1); MFMA(acc[sub][1], aL, bH1);
            }
        }
#pragma unroll
        for (int kk = 4; kk < 8; ++kk) {           // A = h1bf global (K 128..255)
            short8 bH0 = *(const short8*)(Wp + kk * 8192);
            short8 bH1 = *(const short8*)(Wp + kk * 8192 + 128);
            short8 bL0 = *(const short8*)(Wp + kk * 8192 + 4096);
            short8 bL1 = *(const short8*)(Wp + kk * 8192 + 4096 + 128);
#pragma unroll
            for (int sub = 0; sub < 2; ++sub) {
                int row = i0 + sub * 16 + mr; if (row > n - 1) row = n - 1;
                short8 aH = *(const short8*)(h1bf + (size_t)row * 128 + (kk - 4) * 32 + kc * 8);
                MFMA(acc[sub][0], aH, bH0); MFMA(acc[sub][0], aH, bL0);
                MFMA(acc[sub][1], aH, bH1); MFMA(acc[sub][1], aH, bL1);
            }
        }
    }
    __syncthreads();   // all agg reads complete -> safe to overwrite with h2

#pragma unroll
    for (int tt = 0; tt < 2; ++tt) {
        int c = (t0 + tt) * 16 + mr;
        float bv = brel[c];
#pragma unroll
        for (int sub = 0; sub < 2; ++sub)
#pragma unroll
            for (int j = 0; j < 4; ++j) {
                int rl = sub * 16 + kc * 4 + j;
                agg[rl * 132 + c] = LEAKY(acc[sub][tt][j] + bv);
            }
    }
    __syncthreads();

    // ---- GEMM2: gate over [h2|x] ----
    f32x4 as[2][2] = {}, at_[2][2] = {};
    {
        const ushort* Wp = Wgf + kc * 1024 + t0 * 128 + mr * 8;
#pragma unroll
        for (int kk = 0; kk < 4; ++kk) {           // A = LDS h2 f32 (K 0..127)
            short8 sH0 = *(const short8*)(Wp + kk * 16384);
            short8 sH1 = *(const short8*)(Wp + kk * 16384 + 128);
            short8 sL0 = *(const short8*)(Wp + kk * 16384 + 4096);
            short8 sL1 = *(const short8*)(Wp + kk * 16384 + 4096 + 128);
            short8 tH0 = *(const short8*)(Wp + kk * 16384 + 8192);
            short8 tH1 = *(const short8*)(Wp + kk * 16384 + 8192 + 128);
            short8 tL0 = *(const short8*)(Wp + kk * 16384 + 12288);
            short8 tL1 = *(const short8*)(Wp + kk * 16384 + 12288 + 128);
#pragma unroll
            for (int sub = 0; sub < 2; ++sub) {
                short8 aH, aL;
                split8(&agg[(sub * 16 + mr) * 132 + kk * 32 + kc * 8], aH, aL);
                MFMA(as[sub][0], aH, sH0); MFMA(as[sub][0], aH, sL0); MFMA(as[sub][0], aL, sH0);
                MFMA(as[sub][1], aH, sH1); MFMA(as[sub][1], aH, sL1); MFMA(as[sub][1], aL, sH1);
                MFMA(at_[sub][0], aH, tH0); MFMA(at_[sub][0], aH, tL0); MFMA(at_[sub][0], aL, tH0);
                MFMA(at_[sub][1], aH, tH1); MFMA(at_[sub][1], aH, tL1); MFMA(at_[sub][1], aL, tH1);
            }
        }
#pragma unroll
        for (int kk = 4; kk < 6; ++kk) {           // A = x (K 128..191), exact split
            short8 sH0 = *(const short8*)(Wp + kk * 16384);
            short8 sH1 = *(const short8*)(Wp + kk * 16384 + 128);
            short8 sL0 = *(const short8*)(Wp + kk * 16384 + 4096);
            short8 sL1 = *(const short8*)(Wp + kk * 16384 + 4096 + 128);
            short8 tH0 = *(const short8*)(Wp + kk * 16384 + 8192);
            short8 tH1 = *(const short8*)(Wp + kk * 16384 + 8192 + 128);
            short8 tL0 = *(const short8*)(Wp + kk * 16384 + 12288);
            short8 tL1 = *(const short8*)(Wp + kk * 16384 + 12288 + 128);
#pragma unroll
            for (int sub = 0; sub < 2; ++sub) {
                int row = i0 + sub * 16 + mr; if (row > n - 1) row = n - 1;
                short8 aH, aL;
                split8(x + (size_t)row * 64 + (kk - 4) * 32 + kc * 8, aH, aL);
                MFMA(as[sub][0], aH, sH0); MFMA(as[sub][0], aH, sL0); MFMA(as[sub][0], aL, sH0);
                MFMA(as[sub][1], aH, sH1); MFMA(as[sub][1], aH, sL1); MFMA(as[sub][1], aL, sH1);
                MFMA(at_[sub][0], aH, tH0); MFMA(at_[sub][0], aH, tL0); MFMA(at_[sub][0], aL, tH0);
                MFMA(at_[sub][1], aH, tH1); MFMA(at_[sub][1], aH, tL1); MFMA(at_[sub][1], aL, tH1);
            }
        }
    }
    __syncthreads();   // h2 LDS reads complete -> safe to alias gs

    // ---- gate epilogue ----
#pragma unroll
    for (int tt = 0; tt < 2; ++tt) {
        int c = (t0 + tt) * 16 + mr;
        float bsv = bsig[c], btv = btanh[c];
#pragma unroll
        for (int sub = 0; sub < 2; ++sub)
#pragma unroll
            for (int j = 0; j < 4; ++j) {
                int rl = sub * 16 + kc * 4 + j;
                float s = as[sub][tt][j] + bsv;
                s = fminf(fmaxf(s, -30.f), 30.f);
                float ta = at_[sub][tt][j] + btv;
                ta = fminf(fmaxf(ta, -15.f), 15.f);
                float e2 = __expf(2.f * ta);
                float th = (e2 - 1.f) / (e2 + 1.f);
                gs[rl * 128 + c] = th / (1.f + __expf(s));
            }
    }
    __syncthreads();

    // ---- run-compressed pooling ----
    int j = tid & 127;
    int m0 = (tid >> 7) * 16;
    float acc2 = 0.f;
    int cur = -1;
    for (int m = m0; m < m0 + 16; ++m) {
        int b = bS[m];
        if (b < 0) break;
        if (b != cur) {
            if (cur >= 0) atomicAdd(&pooled[(size_t)cur * 128 + j], acc2);
            cur = b;
            acc2 = 0.f;
        }
        acc2 += gs[m * 128 + j];
    }
    if (cur >= 0) atomicAdd(&pooled[(size_t)cur * 128 + j], acc2);
}

// ---------------------------------------------------------------------------
// Final per-graph MLP
// ---------------------------------------------------------------------------
__global__ __launch_bounds__(256) void mlp_kernel(
    const float* __restrict__ pooled,
    const float* __restrict__ Wf1, const float* __restrict__ bf1,
    const float* __restrict__ Wf2, const float* __restrict__ bf2,
    const float* __restrict__ Wout, const float* __restrict__ bout,
    float* __restrict__ out)
{
    __shared__ float p[128];
    __shared__ float f1[128];
    __shared__ float f2[258];
    __shared__ float red[4];

    int g = blockIdx.x;
    int tid = threadIdx.x;

    if (tid < 128) p[tid] = pooled[(size_t)g * 128 + tid];
    __syncthreads();

    if (tid < 128) {
        float a = bf1[tid];
        for (int k = 0; k < 128; ++k) a += p[k] * Wf1[k * 128 + tid];
        f1[tid] = LEAKY(a);
    }
    __syncthreads();

    for (int j = tid; j < 258; j += 256) {
        float a = bf2[j];
        for (int k = 0; k < 128; ++k) a += f1[k] * Wf2[k * 258 + j];
        f2[j] = LEAKY(a);
    }
    __syncthreads();

    float a = 0.f;
    for (int j = tid; j < 258; j += 256) a += f2[j] * Wout[j];
#pragma unroll
    for (int off = 32; off > 0; off >>= 1) a += __shfl_down(a, off, 64);
    if ((tid & 63) == 0) red[tid >> 6] = a;
    __syncthreads();
    if (tid == 0) {
        float v = red[0] + red[1] + red[2] + red[3] + bout[0];
        out[g] = 1.f / (1.f + expf(-v));
    }
}

// ---------------------------------------------------------------------------
extern "C" void kernel_launch(void* const* d_in, const int* in_sizes, int n_in,
                              void* d_out, int out_size, void* d_ws, size_t ws_size,
                              hipStream_t stream)
{
    const float* x     = (const float*)d_in[0];
    const int*   ei    = (const int*)d_in[1];
    const int*   batch = (const int*)d_in[2];
    const float* ea    = (const float*)d_in[3];
    const float* Wrel1 = (const float*)d_in[4];
    const float* brel1 = (const float*)d_in[5];
    const float* Wroot1= (const float*)d_in[6];
    const float* Wrel2 = (const float*)d_in[7];
    const float* brel2 = (const float*)d_in[8];
    const float* Wroot2= (const float*)d_in[9];
    const float* Wsig  = (const float*)d_in[10];
    const float* bsig  = (const float*)d_in[11];
    const float* Wtanh = (const float*)d_in[12];
    const float* btanh = (const float*)d_in[13];
    const float* Wf1   = (const float*)d_in[14];
    const float* bf1   = (const float*)d_in[15];
    const float* Wf2   = (const float*)d_in[16];
    const float* bf2   = (const float*)d_in[17];
    const float* Wout  = (const float*)d_in[18];
    const float* bout  = (const float*)d_in[19];

    int N = in_sizes[2];
    int E = in_sizes[3];
    int NB = (N + 511) / 512;      // buckets of 512 nodes (N <= 131072)

    char* base = (char*)d_ws;
    size_t off = 0;
    auto alloc = [&](size_t bytes) {
        char* p = base + off;
        off += (bytes + 255) & ~(size_t)255;
        return p;
    };
    ushort*   h1bf  = (ushort*)alloc((size_t)N * 128 * 2);
    ushort*   xbf   = (ushort*)alloc((size_t)N * 64 * 2);
    int*      rowptr= (int*)alloc((size_t)(N + 1) * 4);
    int*      bhist = (int*)alloc(256 * 4);
    int*      bptr  = (int*)alloc(257 * 4);
    int*      bcur  = (int*)alloc(256 * 4);
    int2*     csw   = (int2*)alloc((size_t)E * 8);
    int2*     csw2  = (int2*)alloc((size_t)E * 8);
    ushort*   W1f   = (ushort*)alloc(32768 * 2);
    ushort*   W2f   = (ushort*)alloc(65536 * 2);
    ushort*   Wgf   = (ushort*)alloc(98304 * 2);
    float*    pooled= (float*)alloc(256 * 128 * 4);

    int cblk = (N + 31) / 32;
    int ablk = (E + CHUNK - 1) / CHUNK;

    hipMemsetAsync(bhist, 0, 256 * sizeof(int), stream);
    hipMemsetAsync(bcur, 0, 256 * sizeof(int), stream);
    hipMemsetAsync(pooled, 0, (size_t)256 * 128 * sizeof(float), stream);

    prep_weights_kernel<<<768, 256, 0, stream>>>(Wrel1, Wroot1, Wrel2, Wroot2,
                                                 Wsig, Wtanh, W1f, W2f, Wgf);
    xbf_kernel<<<(N * 16 + 255) / 256, 256, 0, stream>>>(x, xbf, N * 16);

    // ---- CSR build v2 ----
    bhist_kernel<<<ablk, 256, 0, stream>>>(ei, bhist, E);
    bscan_kernel<<<1, 256, 0, stream>>>(bhist, bptr, E);
    partA_kernel<<<ablk, 256, 0, stream>>>(ei, ea, bptr, bcur, csw2, E, NB);
    partB_kernel<<<NB, 256, 0, stream>>>(csw2, bptr, rowptr, csw, N, E);

    // ---- fused conv1 (gather + GEMM) ----
    conv1_fused_kernel<<<cblk, 256, 0, stream>>>(x, xbf, rowptr, csw,
                                                 W1f, brel1, h1bf, N);

    // ---- fused conv2 + gate + pool (gather + 2 GEMMs) ----
    conv2_gate_kernel<<<cblk, 256, 0, stream>>>(h1bf, x, rowptr, csw,
                                                W2f, brel2, Wgf, bsig, btanh,
                                                batch, pooled, N);

    // ---- final MLP ----
    mlp_kernel<<<256, 256, 0, stream>>>(pooled, Wf1, bf1, Wf2, bf2, Wout, bout,
                                        (float*)d_out);
}